// Round 16
// baseline (404.565 us; speedup 1.0000x reference)
//
#include <hip/hip_runtime.h>
#include <hip/hip_bf16.h>
#include <stdint.h>

typedef __bf16 bf16;
typedef bf16 bf16x8 __attribute__((ext_vector_type(8)));
typedef float f32x4 __attribute__((ext_vector_type(4)));

#define B_ 2
#define L_ 2046
#define H_ 16
#define NW_ 682
#define LP_ 2048
#define NWP_ 704
#define M_ (B_*L_)
#define SCALE_ 0.125f

__device__ inline bf16x8 zf8() {
  bf16x8 v;
#pragma unroll
  for (int e = 0; e < 8; ++e) v[e] = (bf16)0.0f;
  return v;
}

__device__ inline uint32_t pkbf(float a, float b) {
  uint16_t ua = __builtin_bit_cast(uint16_t, (bf16)a);
  uint16_t ub = __builtin_bit_cast(uint16_t, (bf16)b);
  return (uint32_t)ua | ((uint32_t)ub << 16);
}
__device__ inline float upk_lo(uint32_t u) { return __builtin_bit_cast(float, u << 16); }
__device__ inline float upk_hi(uint32_t u) { return __builtin_bit_cast(float, u & 0xffff0000u); }

// LDS-only barrier: wait LDS ops, DO NOT drain vmcnt (global stores stay in flight).
__device__ inline void ldsbar() {
  asm volatile("s_waitcnt lgkmcnt(0)" ::: "memory");
  __builtin_amdgcn_sched_barrier(0);
  __builtin_amdgcn_s_barrier();
  __builtin_amdgcn_sched_barrier(0);
}

// ---------------- cast f32 -> bf16 (vectorized x4) ----------------
__global__ __launch_bounds__(256) void cast4(const float* __restrict__ in,
                                             bf16* __restrict__ out, int n) {
  int i = (blockIdx.x * 256 + threadIdx.x) * 4;
  if (i + 3 < n) {
    float4 v = *reinterpret_cast<const float4*>(in + i);
    bf16 tmp[4];
    tmp[0] = (bf16)v.x; tmp[1] = (bf16)v.y; tmp[2] = (bf16)v.z; tmp[3] = (bf16)v.w;
    *reinterpret_cast<uint64_t*>(out + i) = *reinterpret_cast<const uint64_t*>(tmp);
  } else {
    for (; i < n; ++i) out[i] = (bf16)in[i];
  }
}

// ---------------- q = x @ Wq^T + bq : LDS-tiled MFMA GEMM (64x128 tile, BK=32) ----------------
__global__ __launch_bounds__(256) void qgemm_t(const bf16* __restrict__ X,
                                               const bf16* __restrict__ W,
                                               const float* __restrict__ bq,
                                               bf16* __restrict__ Q) {
  __shared__ bf16 As[64 * 40];
  __shared__ bf16 Bs[128 * 40];
  int t = threadIdx.x, lane = t & 63, w = t >> 6;
  int lid = lane & 15, g = lane >> 4;
  int m0 = blockIdx.x * 64, n0 = blockIdx.y * 128;
  int wm = (w >> 1) * 32, wn = (w & 1) * 64;
  f32x4 z4 = {0.f, 0.f, 0.f, 0.f};
  f32x4 acc[2][4];
#pragma unroll
  for (int mi = 0; mi < 2; ++mi)
#pragma unroll
    for (int ni = 0; ni < 4; ++ni) acc[mi][ni] = z4;
  int r1 = t >> 2, c1 = t & 3;
  for (int k0 = 0; k0 < 1024; k0 += 32) {
    int ga = m0 + r1; if (ga >= M_) ga = M_ - 1;
    bf16x8 av = *reinterpret_cast<const bf16x8*>(X + (size_t)ga * 1024 + k0 + c1 * 8);
    bf16x8 bv1 = *reinterpret_cast<const bf16x8*>(W + (size_t)(n0 + r1) * 1024 + k0 + c1 * 8);
    bf16x8 bv2 = *reinterpret_cast<const bf16x8*>(W + (size_t)(n0 + 64 + r1) * 1024 + k0 + c1 * 8);
    __syncthreads();
    *reinterpret_cast<bf16x8*>(As + r1 * 40 + c1 * 8) = av;
    *reinterpret_cast<bf16x8*>(Bs + r1 * 40 + c1 * 8) = bv1;
    *reinterpret_cast<bf16x8*>(Bs + (64 + r1) * 40 + c1 * 8) = bv2;
    __syncthreads();
    bf16x8 af[2], bfr[4];
#pragma unroll
    for (int mi = 0; mi < 2; ++mi)
      af[mi] = *reinterpret_cast<const bf16x8*>(As + (wm + mi * 16 + lid) * 40 + g * 8);
#pragma unroll
    for (int ni = 0; ni < 4; ++ni)
      bfr[ni] = *reinterpret_cast<const bf16x8*>(Bs + (wn + ni * 16 + lid) * 40 + g * 8);
#pragma unroll
    for (int mi = 0; mi < 2; ++mi)
#pragma unroll
      for (int ni = 0; ni < 4; ++ni)
        acc[mi][ni] = __builtin_amdgcn_mfma_f32_16x16x32_bf16(af[mi], bfr[ni], acc[mi][ni], 0, 0, 0);
  }
  float bias[4];
#pragma unroll
  for (int ni = 0; ni < 4; ++ni) bias[ni] = bq[n0 + wn + ni * 16 + lid];
#pragma unroll
  for (int mi = 0; mi < 2; ++mi)
#pragma unroll
    for (int r = 0; r < 4; ++r) {
      int row = m0 + wm + mi * 16 + g * 4 + r;
      if (row < M_) {
#pragma unroll
        for (int ni = 0; ni < 4; ++ni)
          Q[(size_t)row * 1024 + n0 + wn + ni * 16 + lid] = (bf16)(acc[mi][ni][r] + bias[ni]);
      }
    }
}

// ---------------- global-head K/V projections; K row-major, V TRANSPOSED out ----------------
__global__ __launch_bounds__(256) void proj_g32(const float* __restrict__ x,
    const float* __restrict__ Wk, const float* __restrict__ bk,
    const float* __restrict__ Wv, const float* __restrict__ bv,
    bf16* __restrict__ KGP, bf16* __restrict__ VGT) {
  __shared__ float xs[64][64];
  __shared__ float wks[64][65];
  __shared__ float wvs[64][65];
  int t = threadIdx.x;
  int lb = blockIdx.x, bh = blockIdx.y;
  int b = bh >> 3, h = bh & 7;
  int l0 = lb * 64;
  for (int idx = t; idx < 4096; idx += 256) {
    int r = idx >> 6, c = idx & 63;
    int l = l0 + r;
    xs[r][c] = (l < L_) ? x[((size_t)b * L_ + l) * 1024 + h * 64 + c] : 0.0f;
    wks[r][c] = Wk[(size_t)h * 4096 + idx];
    wvs[r][c] = Wv[(size_t)h * 4096 + idx];
  }
  __syncthreads();
  int o = t & 63, lg = t >> 6;
  float kbias = bk[h * 64 + o], vbias = bv[h * 64 + o];
  float vacc[16];
  const size_t outb = (size_t)bh * LP_ * 64;
  for (int ls = 0; ls < 16; ++ls) {
    int l = lg * 16 + ls;
    float ka = kbias, va = vbias;
#pragma unroll
    for (int i = 0; i < 64; ++i) {
      float xv = xs[l][i];
      ka = fmaf(xv, wks[o][i], ka);
      va = fmaf(xv, wvs[o][i], va);
    }
    KGP[outb + (size_t)(l0 + l) * 64 + o] = (bf16)ka;
    vacc[ls] = va;
  }
  __syncthreads();
#pragma unroll
  for (int ls = 0; ls < 16; ++ls) wvs[o][lg * 16 + ls] = vacc[ls];
  __syncthreads();
  for (int idx = t; idx < 4096; idx += 256) {
    int oo = idx >> 6, ll = idx & 63;
    VGT[(size_t)bh * 64 * LP_ + (size_t)oo * LP_ + l0 + ll] = (bf16)wvs[oo][ll];
  }
}

// ---------------- local-head window-avg + K/V projections; V TRANSPOSED out ----------------
__global__ __launch_bounds__(256) void proj_l32(const float* __restrict__ x,
    const float* __restrict__ Wk, const float* __restrict__ bk,
    const float* __restrict__ Wv, const float* __restrict__ bv,
    bf16* __restrict__ KLP, bf16* __restrict__ VLT) {
  __shared__ float xs[64][64];
  __shared__ float wks[64][65];
  __shared__ float wvs[64][65];
  int t = threadIdx.x;
  int nb = blockIdx.x, bh = blockIdx.y;
  int b = bh >> 3, h = bh & 7;
  int n0 = nb * 64;
  int hh = 8 + h;
  for (int idx = t; idx < 4096; idx += 256) {
    int r = idx >> 6, c = idx & 63;
    int n = n0 + r;
    float v = 0.0f;
    if (n < NW_) {
      size_t base = ((size_t)b * L_ + 3 * n) * 1024 + hh * 64 + c;
      v = (x[base] + x[base + 1024] + x[base + 2048]) * (1.0f / 3.0f);
    }
    xs[r][c] = v;
    wks[r][c] = Wk[(size_t)hh * 4096 + idx];
    wvs[r][c] = Wv[(size_t)hh * 4096 + idx];
  }
  __syncthreads();
  int o = t & 63, lg = t >> 6;
  float kbias = bk[hh * 64 + o], vbias = bv[hh * 64 + o];
  float vacc[16];
  const size_t outb = (size_t)bh * NWP_ * 64;
  for (int ls = 0; ls < 16; ++ls) {
    int l = lg * 16 + ls;
    float ka = kbias, va = vbias;
#pragma unroll
    for (int i = 0; i < 64; ++i) {
      float xv = xs[l][i];
      ka = fmaf(xv, wks[o][i], ka);
      va = fmaf(xv, wvs[o][i], va);
    }
    KLP[outb + (size_t)(n0 + l) * 64 + o] = (bf16)ka;
    vacc[ls] = va;
  }
  __syncthreads();
#pragma unroll
  for (int ls = 0; ls < 16; ++ls) wvs[o][lg * 16 + ls] = vacc[ls];
  __syncthreads();
  for (int idx = t; idx < 4096; idx += 256) {
    int oo = idx >> 6, ll = idx & 63;
    VLT[(size_t)bh * 64 * NWP_ + (size_t)oo * NWP_ + n0 + ll] = (bf16)wvs[oo][ll];
  }
}

// ---------------- mask precompute: bit-packed (1 = masked) — R3-verified ----------------
__global__ __launch_bounds__(256) void maskprep(const float* __restrict__ mask,
                                                uint64_t* __restrict__ gm,
                                                uint64_t* __restrict__ wm) {
  int row = blockIdx.x * 4 + (threadIdx.x >> 6);  // b*L + l
  int lane = threadIdx.x & 63;
  if (row >= B_ * L_) return;
  int b = row / L_, l = row % L_;
  const float* mr = mask + (size_t)b * L_ * L_ + (size_t)l * L_;
  for (int w = 0; w < 32; ++w) {
    int m = w * 64 + lane;
    bool masked = (m >= L_) ? true : (mr[m] == 0.0f);
    uint64_t bal = __ballot(masked);
    if (lane == 0) gm[(size_t)row * 32 + w] = bal;
  }
  for (int w = 0; w < 11; ++w) {
    int n = w * 64 + lane;
    bool lmask = true;
    if (n < NW_) {
      float s = mr[3 * n] + mr[3 * n + 1] + mr[3 * n + 2];
      lmask = !(s >= 2.0f);
    }
    uint64_t bal = __ballot(lmask);
    if (lane == 0) wm[(size_t)row * 11 + w] = bal;
  }
}

// ---------------- FUSED global, 8-wave: QK^T -> softmax -> pg + PV (V^T direct) ----------------
__global__ __launch_bounds__(512, 2) void attn_gf(const bf16* __restrict__ Q,
    const bf16* __restrict__ K, const bf16* __restrict__ VT,
    const uint64_t* __restrict__ GM,
    float* __restrict__ OP, float* __restrict__ OV) {
  __shared__ float sums[128];
  __shared__ float strip2[2][16][257];
  int t = threadIdx.x;
  int lane = t & 63, wave = t >> 6;   // 8 waves
  int lid = lane & 15, g = lane >> 4;
  int q0 = blockIdx.x * 16;
  int bh = blockIdx.y;
  int b = bh >> 3, h = bh & 7;
  const bf16* qb = Q + (size_t)b * L_ * 1024 + h * 64;
  const bf16* kb = K + (size_t)bh * LP_ * 64;
  const bf16* vtg = VT + (size_t)bh * 64 * LP_;   // V^T [d][m]
  const uint64_t* gmb = GM + (size_t)b * L_ * 32;

  bf16x8 aq0 = zf8(), aq1 = zf8();
  {
    int qr = q0 + lid;
    if (qr < L_) {
      aq0 = *reinterpret_cast<const bf16x8*>(qb + (size_t)qr * 1024 + g * 8);
      aq1 = *reinterpret_cast<const bf16x8*>(qb + (size_t)qr * 1024 + 32 + g * 8);
    }
  }
  // ---- phase 1: single-pass QK^T, P in registers ----
  uint32_t preg[32];
  float rs[4] = {0.f, 0.f, 0.f, 0.f};
#pragma unroll
  for (int it = 0; it < 8; ++it) {
    int p = it * 8 + wave;
    int c0 = p * 32;
    int col0 = c0 + lid, col1 = c0 + 16 + lid;
    bf16x8 bka0 = *reinterpret_cast<const bf16x8*>(kb + (size_t)col0 * 64 + g * 8);
    bf16x8 bka1 = *reinterpret_cast<const bf16x8*>(kb + (size_t)col0 * 64 + 32 + g * 8);
    bf16x8 bkb0 = *reinterpret_cast<const bf16x8*>(kb + (size_t)col1 * 64 + g * 8);
    bf16x8 bkb1 = *reinterpret_cast<const bf16x8*>(kb + (size_t)col1 * 64 + 32 + g * 8);
    f32x4 acc0 = {0.f, 0.f, 0.f, 0.f}, acc1 = {0.f, 0.f, 0.f, 0.f};
    acc0 = __builtin_amdgcn_mfma_f32_16x16x32_bf16(aq0, bka0, acc0, 0, 0, 0);
    acc0 = __builtin_amdgcn_mfma_f32_16x16x32_bf16(aq1, bka1, acc0, 0, 0, 0);
    acc1 = __builtin_amdgcn_mfma_f32_16x16x32_bf16(aq0, bkb0, acc1, 0, 0, 0);
    acc1 = __builtin_amdgcn_mfma_f32_16x16x32_bf16(aq1, bkb1, acc1, 0, 0, 0);
    int wi = c0 >> 6;
    int bit0 = c0 & 32;
#pragma unroll
    for (int r = 0; r < 4; ++r) {
      int qr = q0 + g * 4 + r;
      uint64_t w = (qr < L_) ? gmb[(size_t)qr * 32 + wi] : ~0ull;
      float pv0 = ((w >> (bit0 + lid)) & 1) ? 0.0f : __expf(acc0[r] * SCALE_);
      float pv1 = ((w >> (bit0 + 16 + lid)) & 1) ? 0.0f : __expf(acc1[r] * SCALE_);
      rs[r] += pv0 + pv1;
      preg[it * 4 + r] = pkbf(pv0, pv1);
    }
  }
#pragma unroll
  for (int off = 8; off >= 1; off >>= 1)
#pragma unroll
    for (int r = 0; r < 4; ++r) rs[r] += __shfl_xor(rs[r], off, 64);
  if (lid == 0) {
#pragma unroll
    for (int r = 0; r < 4; ++r) sums[wave * 16 + g * 4 + r] = rs[r];
  }
  ldsbar();
  float invr[4];
#pragma unroll
  for (int r = 0; r < 4; ++r) {
    int row = g * 4 + r;
    float s = 0.f;
#pragma unroll
    for (int ww = 0; ww < 8; ++ww) s += sums[ww * 16 + row];
    invr[r] = (s > 0.f) ? 1.0f / s : 0.0f;
  }
  // ---- phase 2: ping-pong strip; PV + pg store; LDS-only barriers ----
  int orow = t >> 5;            // 0..15
  int qrT = q0 + orow;
  bool rowok = (qrT < L_);
  const size_t rowb = (size_t)bh * L_ * L_ + (size_t)(rowok ? qrT : 0) * L_;
  int c8 = (t & 31) * 8;
  f32x4 vacc[4];
  f32x4 z4 = {0.f, 0.f, 0.f, 0.f};
#pragma unroll
  for (int dg = 0; dg < 4; ++dg) vacc[dg] = z4;
#pragma unroll
  for (int it = 0; it < 8; ++it) {
    float* sbuf = &strip2[it & 1][0][0];
    int mb0 = it * 256;
#pragma unroll
    for (int r = 0; r < 4; ++r) {
      uint32_t u = preg[it * 4 + r];
      sbuf[(g * 4 + r) * 257 + wave * 32 + lid] = upk_lo(u) * invr[r];
      sbuf[(g * 4 + r) * 257 + wave * 32 + 16 + lid] = upk_hi(u) * invr[r];
    }
    ldsbar();
    // PV first (feed the matrix pipe), then pg stores (fire-and-forget)
    bf16x8 af;
#pragma unroll
    for (int e = 0; e < 8; ++e) af[e] = (bf16)sbuf[lid * 257 + wave * 32 + g * 8 + e];
#pragma unroll
    for (int dg = 0; dg < 4; ++dg) {
      bf16x8 bv8 = *reinterpret_cast<const bf16x8*>(vtg + (size_t)(dg * 16 + lid) * LP_ + mb0 + wave * 32 + g * 8);
      vacc[dg] = __builtin_amdgcn_mfma_f32_16x16x32_bf16(af, bv8, vacc[dg], 0, 0, 0);
    }
    int col = mb0 + c8;
    if (rowok) {
#pragma unroll
      for (int pr = 0; pr < 4; ++pr) {
        int cc = c8 + pr * 2;
        if (col + pr * 2 + 1 < L_) {
          float2 o2 = make_float2(sbuf[orow * 257 + cc], sbuf[orow * 257 + cc + 1]);
          *reinterpret_cast<float2*>(OP + rowb + col + pr * 2) = o2;
        }
      }
    }
  }
  ldsbar();
  // ---- cross-wave OV reduce via strip2[0] ----
  float* red = &strip2[0][0][0];
#pragma unroll
  for (int wsel = 0; wsel < 8; ++wsel) {
    if (wave == wsel) {
#pragma unroll
      for (int dg = 0; dg < 4; ++dg)
#pragma unroll
        for (int r = 0; r < 4; ++r) {
          if (wsel == 0) red[(g * 4 + r) * 257 + dg * 16 + lid] = vacc[dg][r];
          else           red[(g * 4 + r) * 257 + dg * 16 + lid] += vacc[dg][r];
        }
    }
    ldsbar();
  }
  float* ob = OV + (((size_t)b * 16 + h) * L_) * 64;
  for (int idx = t; idx < 1024; idx += 512) {
    int r = idx >> 6, d = idx & 63;
    int qr = q0 + r;
    if (qr < L_) ob[(size_t)qr * 64 + d] = red[r * 257 + d];
  }
}

// ---------------- FUSED local, 8-wave (V^T direct) ----------------
__global__ __launch_bounds__(512, 2) void attn_lf(const bf16* __restrict__ Q,
    const bf16* __restrict__ K, const bf16* __restrict__ VT,
    const uint64_t* __restrict__ WM,
    float* __restrict__ OP, float* __restrict__ OV) {
  __shared__ float sums[128];
  __shared__ float strip2[2][16][257];
  int t = threadIdx.x;
  int lane = t & 63, wave = t >> 6;
  int lid = lane & 15, g = lane >> 4;
  int q0 = blockIdx.x * 16;
  int bh = blockIdx.y;
  int b = bh >> 3, h = bh & 7;
  const bf16* qb = Q + (size_t)b * L_ * 1024 + (8 + h) * 64;
  const bf16* kb = K + (size_t)bh * NWP_ * 64;
  const bf16* vtg = VT + (size_t)bh * 64 * NWP_;
  const uint64_t* wmb = WM + (size_t)b * L_ * 11;

  bf16x8 aq0 = zf8(), aq1 = zf8();
  {
    int qr = q0 + lid;
    if (qr < L_) {
      aq0 = *reinterpret_cast<const bf16x8*>(qb + (size_t)qr * 1024 + g * 8);
      aq1 = *reinterpret_cast<const bf16x8*>(qb + (size_t)qr * 1024 + 32 + g * 8);
    }
  }
  uint32_t preg[12];
  float rs[4] = {0.f, 0.f, 0.f, 0.f};
#pragma unroll
  for (int it = 0; it < 3; ++it) {
    int p = it * 8 + wave;
    if (p < 22) {
      int c0 = p * 32;
      int col0 = c0 + lid, col1 = c0 + 16 + lid;
      bf16x8 bka0 = *reinterpret_cast<const bf16x8*>(kb + (size_t)col0 * 64 + g * 8);
      bf16x8 bka1 = *reinterpret_cast<const bf16x8*>(kb + (size_t)col0 * 64 + 32 + g * 8);
      bf16x8 bkb0 = *reinterpret_cast<const bf16x8*>(kb + (size_t)col1 * 64 + g * 8);
      bf16x8 bkb1 = *reinterpret_cast<const bf16x8*>(kb + (size_t)col1 * 64 + 32 + g * 8);
      f32x4 acc0 = {0.f, 0.f, 0.f, 0.f}, acc1 = {0.f, 0.f, 0.f, 0.f};
      acc0 = __builtin_amdgcn_mfma_f32_16x16x32_bf16(aq0, bka0, acc0, 0, 0, 0);
      acc0 = __builtin_amdgcn_mfma_f32_16x16x32_bf16(aq1, bka1, acc0, 0, 0, 0);
      acc1 = __builtin_amdgcn_mfma_f32_16x16x32_bf16(aq0, bkb0, acc1, 0, 0, 0);
      acc1 = __builtin_amdgcn_mfma_f32_16x16x32_bf16(aq1, bkb1, acc1, 0, 0, 0);
      int wi = c0 >> 6;
      int bit0 = c0 & 32;
#pragma unroll
      for (int r = 0; r < 4; ++r) {
        int qr = q0 + g * 4 + r;
        uint64_t w = (qr < L_) ? wmb[(size_t)qr * 11 + wi] : ~0ull;
        float pv0 = ((w >> (bit0 + lid)) & 1) ? 0.0f : __expf(acc0[r] * SCALE_);
        float pv1 = ((w >> (bit0 + 16 + lid)) & 1) ? 0.0f : __expf(acc1[r] * SCALE_);
        rs[r] += pv0 + pv1;
        preg[it * 4 + r] = pkbf(pv0, pv1);
      }
    }
  }
#pragma unroll
  for (int off = 8; off >= 1; off >>= 1)
#pragma unroll
    for (int r = 0; r < 4; ++r) rs[r] += __shfl_xor(rs[r], off, 64);
  if (lid == 0) {
#pragma unroll
    for (int r = 0; r < 4; ++r) sums[wave * 16 + g * 4 + r] = rs[r];
  }
  ldsbar();
  float invr[4];
#pragma unroll
  for (int r = 0; r < 4; ++r) {
    int row = g * 4 + r;
    float s = 0.f;
#pragma unroll
    for (int ww = 0; ww < 8; ++ww) s += sums[ww * 16 + row];
    invr[r] = (s > 0.f) ? 1.0f / s : 0.0f;
  }
  int orow = t >> 5;
  int qrT = q0 + orow;
  bool rowok = (qrT < L_);
  const size_t rowb = (size_t)bh * L_ * NW_ + (size_t)(rowok ? qrT : 0) * NW_;
  int c8 = (t & 31) * 8;
  f32x4 vacc[4];
  f32x4 z4 = {0.f, 0.f, 0.f, 0.f};
#pragma unroll
  for (int dg = 0; dg < 4; ++dg) vacc[dg] = z4;
#pragma unroll
  for (int it = 0; it < 3; ++it) {
    float* sbuf = &strip2[it & 1][0][0];
    int p = it * 8 + wave;
    bool act = (p < 22);
    int mb0 = it * 256;
    if (act) {
#pragma unroll
      for (int r = 0; r < 4; ++r) {
        uint32_t u = preg[it * 4 + r];
        sbuf[(g * 4 + r) * 257 + wave * 32 + lid] = upk_lo(u) * invr[r];
        sbuf[(g * 4 + r) * 257 + wave * 32 + 16 + lid] = upk_hi(u) * invr[r];
      }
    }
    ldsbar();
    if (act) {
      bf16x8 af;
#pragma unroll
      for (int e = 0; e < 8; ++e) af[e] = (bf16)sbuf[lid * 257 + wave * 32 + g * 8 + e];
#pragma unroll
      for (int dg = 0; dg < 4; ++dg) {
        bf16x8 bv8 = *reinterpret_cast<const bf16x8*>(vtg + (size_t)(dg * 16 + lid) * NWP_ + mb0 + wave * 32 + g * 8);
        vacc[dg] = __builtin_amdgcn_mfma_f32_16x16x32_bf16(af, bv8, vacc[dg], 0, 0, 0);
      }
    }
    int col = mb0 + c8;
    if (rowok) {
#pragma unroll
      for (int pr = 0; pr < 4; ++pr) {
        int cc = c8 + pr * 2;
        if (col + pr * 2 + 1 < NW_) {
          float2 o2 = make_float2(sbuf[orow * 257 + cc], sbuf[orow * 257 + cc + 1]);
          *reinterpret_cast<float2*>(OP + rowb + col + pr * 2) = o2;
        }
      }
    }
  }
  ldsbar();
  float* red = &strip2[0][0][0];
#pragma unroll
  for (int wsel = 0; wsel < 8; ++wsel) {
    if (wave == wsel) {
#pragma unroll
      for (int dg = 0; dg < 4; ++dg)
#pragma unroll
        for (int r = 0; r < 4; ++r) {
          if (wsel == 0) red[(g * 4 + r) * 257 + dg * 16 + lid] = vacc[dg][r];
          else           red[(g * 4 + r) * 257 + dg * 16 + lid] += vacc[dg][r];
        }
    }
    ldsbar();
  }
  float* ob = OV + (((size_t)b * 16 + 8 + h) * L_) * 64;
  for (int idx = t; idx < 1024; idx += 512) {
    int r = idx >> 6, d = idx & 63;
    int qr = q0 + r;
    if (qr < L_) ob[(size_t)qr * 64 + d] = red[r * 257 + d];
  }
}

extern "C" void kernel_launch(void* const* d_in, const int* in_sizes, int n_in,
                              void* d_out, int out_size, void* d_ws, size_t ws_size,
                              hipStream_t stream) {
  (void)in_sizes; (void)n_in; (void)out_size; (void)ws_size;
  const float* x    = (const float*)d_in[0];
  const float* mask = (const float*)d_in[1];
  const float* Wq   = (const float*)d_in[2];
  const float* bq   = (const float*)d_in[3];
  const float* Wk   = (const float*)d_in[4];
  const float* bk   = (const float*)d_in[5];
  const float* Wv   = (const float*)d_in[6];
  const float* bv   = (const float*)d_in[7];

  char* ws = (char*)d_ws;
  bf16* qbb     = (bf16*)(ws + 0);            // 8,380,416
  bf16* kgb     = (bf16*)(ws + 8380416);      // 4,194,304
  bf16* vgT     = (bf16*)(ws + 12574720);     // 4,194,304 (V^T [bh][d][m])
  bf16* klb     = (bf16*)(ws + 16769024);     // 1,441,792
  bf16* vlT     = (bf16*)(ws + 18210816);     // 1,441,792 (V^T local)
  uint64_t* gm  = (uint64_t*)(ws + 19652608); // 1,047,552
  uint64_t* wm  = (uint64_t*)(ws + 20700160); // 360,096
  bf16* xbb     = (bf16*)(ws + 21060256);     // 8,380,416 (x in bf16)
  bf16* wqb     = (bf16*)(ws + 29440672);     // 2,097,152 (Wq in bf16)

  float* out    = (float*)d_out;
  float* o_vall = out;                 // (2,16,2046,64)
  float* o_pg   = out + 4190208;       // (2,8,2046,2046)
  float* o_pl   = out + 71168064;      // (2,8,2046,682)

  cast4<<<4092, 256, 0, stream>>>(x, xbb, 4190208);
  cast4<<<1024, 256, 0, stream>>>(Wq, wqb, 1048576);
  qgemm_t<<<dim3(64, 8), 256, 0, stream>>>(xbb, wqb, bq, qbb);
  proj_g32<<<dim3(32, 16), 256, 0, stream>>>(x, Wk, bk, Wv, bv, kgb, vgT);
  proj_l32<<<dim3(11, 16), 256, 0, stream>>>(x, Wk, bk, Wv, bv, klb, vlT);
  maskprep<<<1023, 256, 0, stream>>>(mask, gm, wm);

  attn_gf<<<dim3(128, 16), 512, 0, stream>>>(qbb, kgb, vgT, gm, o_pg, o_vall);
  attn_lf<<<dim3(128, 16), 512, 0, stream>>>(qbb, klb, vlT, wm, o_pl, o_vall);
}

// Round 17
// 386.605 us; speedup vs baseline: 1.0465x; 1.0465x over previous
//
#include <hip/hip_runtime.h>
#include <hip/hip_bf16.h>
#include <stdint.h>

typedef __bf16 bf16;
typedef bf16 bf16x8 __attribute__((ext_vector_type(8)));
typedef float f32x4 __attribute__((ext_vector_type(4)));

#define B_ 2
#define L_ 2046
#define H_ 16
#define NW_ 682
#define LP_ 2048
#define NWP_ 704
#define M_ (B_*L_)
#define SCALE_ 0.125f
#define STR 517        // strip row stride (f32): odd -> <=2-way LDS banks
#define RSTR 68        // reduce-tree d stride
#define RW (16*RSTR)   // reduce-tree per-wave block

__device__ inline bf16x8 zf8() {
  bf16x8 v;
#pragma unroll
  for (int e = 0; e < 8; ++e) v[e] = (bf16)0.0f;
  return v;
}

__device__ inline uint32_t pkbf(float a, float b) {
  uint16_t ua = __builtin_bit_cast(uint16_t, (bf16)a);
  uint16_t ub = __builtin_bit_cast(uint16_t, (bf16)b);
  return (uint32_t)ua | ((uint32_t)ub << 16);
}
__device__ inline float upk_lo(uint32_t u) { return __builtin_bit_cast(float, u << 16); }
__device__ inline float upk_hi(uint32_t u) { return __builtin_bit_cast(float, u & 0xffff0000u); }

// ---------------- cast f32 -> bf16 (vectorized x4) ----------------
__global__ __launch_bounds__(256) void cast4(const float* __restrict__ in,
                                             bf16* __restrict__ out, int n) {
  int i = (blockIdx.x * 256 + threadIdx.x) * 4;
  if (i + 3 < n) {
    float4 v = *reinterpret_cast<const float4*>(in + i);
    bf16 tmp[4];
    tmp[0] = (bf16)v.x; tmp[1] = (bf16)v.y; tmp[2] = (bf16)v.z; tmp[3] = (bf16)v.w;
    *reinterpret_cast<uint64_t*>(out + i) = *reinterpret_cast<const uint64_t*>(tmp);
  } else {
    for (; i < n; ++i) out[i] = (bf16)in[i];
  }
}

// ---------------- q = x @ Wq^T + bq : LDS-tiled MFMA GEMM (64x128 tile, BK=32) ----------------
__global__ __launch_bounds__(256) void qgemm_t(const bf16* __restrict__ X,
                                               const bf16* __restrict__ W,
                                               const float* __restrict__ bq,
                                               bf16* __restrict__ Q) {
  __shared__ bf16 As[64 * 40];
  __shared__ bf16 Bs[128 * 40];
  int t = threadIdx.x, lane = t & 63, w = t >> 6;
  int lid = lane & 15, g = lane >> 4;
  int m0 = blockIdx.x * 64, n0 = blockIdx.y * 128;
  int wm = (w >> 1) * 32, wn = (w & 1) * 64;
  f32x4 z4 = {0.f, 0.f, 0.f, 0.f};
  f32x4 acc[2][4];
#pragma unroll
  for (int mi = 0; mi < 2; ++mi)
#pragma unroll
    for (int ni = 0; ni < 4; ++ni) acc[mi][ni] = z4;
  int r1 = t >> 2, c1 = t & 3;
  for (int k0 = 0; k0 < 1024; k0 += 32) {
    int ga = m0 + r1; if (ga >= M_) ga = M_ - 1;
    bf16x8 av = *reinterpret_cast<const bf16x8*>(X + (size_t)ga * 1024 + k0 + c1 * 8);
    bf16x8 bv1 = *reinterpret_cast<const bf16x8*>(W + (size_t)(n0 + r1) * 1024 + k0 + c1 * 8);
    bf16x8 bv2 = *reinterpret_cast<const bf16x8*>(W + (size_t)(n0 + 64 + r1) * 1024 + k0 + c1 * 8);
    __syncthreads();
    *reinterpret_cast<bf16x8*>(As + r1 * 40 + c1 * 8) = av;
    *reinterpret_cast<bf16x8*>(Bs + r1 * 40 + c1 * 8) = bv1;
    *reinterpret_cast<bf16x8*>(Bs + (64 + r1) * 40 + c1 * 8) = bv2;
    __syncthreads();
    bf16x8 af[2], bfr[4];
#pragma unroll
    for (int mi = 0; mi < 2; ++mi)
      af[mi] = *reinterpret_cast<const bf16x8*>(As + (wm + mi * 16 + lid) * 40 + g * 8);
#pragma unroll
    for (int ni = 0; ni < 4; ++ni)
      bfr[ni] = *reinterpret_cast<const bf16x8*>(Bs + (wn + ni * 16 + lid) * 40 + g * 8);
#pragma unroll
    for (int mi = 0; mi < 2; ++mi)
#pragma unroll
      for (int ni = 0; ni < 4; ++ni)
        acc[mi][ni] = __builtin_amdgcn_mfma_f32_16x16x32_bf16(af[mi], bfr[ni], acc[mi][ni], 0, 0, 0);
  }
  float bias[4];
#pragma unroll
  for (int ni = 0; ni < 4; ++ni) bias[ni] = bq[n0 + wn + ni * 16 + lid];
#pragma unroll
  for (int mi = 0; mi < 2; ++mi)
#pragma unroll
    for (int r = 0; r < 4; ++r) {
      int row = m0 + wm + mi * 16 + g * 4 + r;
      if (row < M_) {
#pragma unroll
        for (int ni = 0; ni < 4; ++ni)
          Q[(size_t)row * 1024 + n0 + wn + ni * 16 + lid] = (bf16)(acc[mi][ni][r] + bias[ni]);
      }
    }
}

// ---------------- global-head K/V projections; K row-major, V TRANSPOSED out ----------------
__global__ __launch_bounds__(256) void proj_g32(const float* __restrict__ x,
    const float* __restrict__ Wk, const float* __restrict__ bk,
    const float* __restrict__ Wv, const float* __restrict__ bv,
    bf16* __restrict__ KGP, bf16* __restrict__ VGT) {
  __shared__ float xs[64][64];
  __shared__ float wks[64][65];
  __shared__ float wvs[64][65];
  int t = threadIdx.x;
  int lb = blockIdx.x, bh = blockIdx.y;
  int b = bh >> 3, h = bh & 7;
  int l0 = lb * 64;
  for (int idx = t; idx < 4096; idx += 256) {
    int r = idx >> 6, c = idx & 63;
    int l = l0 + r;
    xs[r][c] = (l < L_) ? x[((size_t)b * L_ + l) * 1024 + h * 64 + c] : 0.0f;
    wks[r][c] = Wk[(size_t)h * 4096 + idx];
    wvs[r][c] = Wv[(size_t)h * 4096 + idx];
  }
  __syncthreads();
  int o = t & 63, lg = t >> 6;
  float kbias = bk[h * 64 + o], vbias = bv[h * 64 + o];
  float vacc[16];
  const size_t outb = (size_t)bh * LP_ * 64;
  for (int ls = 0; ls < 16; ++ls) {
    int l = lg * 16 + ls;
    float ka = kbias, va = vbias;
#pragma unroll
    for (int i = 0; i < 64; ++i) {
      float xv = xs[l][i];
      ka = fmaf(xv, wks[o][i], ka);
      va = fmaf(xv, wvs[o][i], va);
    }
    KGP[outb + (size_t)(l0 + l) * 64 + o] = (bf16)ka;
    vacc[ls] = va;
  }
  __syncthreads();
#pragma unroll
  for (int ls = 0; ls < 16; ++ls) wvs[o][lg * 16 + ls] = vacc[ls];
  __syncthreads();
  for (int idx = t; idx < 4096; idx += 256) {
    int oo = idx >> 6, ll = idx & 63;
    VGT[(size_t)bh * 64 * LP_ + (size_t)oo * LP_ + l0 + ll] = (bf16)wvs[oo][ll];
  }
}

// ---------------- local-head window-avg + K/V projections; V TRANSPOSED out ----------------
__global__ __launch_bounds__(256) void proj_l32(const float* __restrict__ x,
    const float* __restrict__ Wk, const float* __restrict__ bk,
    const float* __restrict__ Wv, const float* __restrict__ bv,
    bf16* __restrict__ KLP, bf16* __restrict__ VLT) {
  __shared__ float xs[64][64];
  __shared__ float wks[64][65];
  __shared__ float wvs[64][65];
  int t = threadIdx.x;
  int nb = blockIdx.x, bh = blockIdx.y;
  int b = bh >> 3, h = bh & 7;
  int n0 = nb * 64;
  int hh = 8 + h;
  for (int idx = t; idx < 4096; idx += 256) {
    int r = idx >> 6, c = idx & 63;
    int n = n0 + r;
    float v = 0.0f;
    if (n < NW_) {
      size_t base = ((size_t)b * L_ + 3 * n) * 1024 + hh * 64 + c;
      v = (x[base] + x[base + 1024] + x[base + 2048]) * (1.0f / 3.0f);
    }
    xs[r][c] = v;
    wks[r][c] = Wk[(size_t)hh * 4096 + idx];
    wvs[r][c] = Wv[(size_t)hh * 4096 + idx];
  }
  __syncthreads();
  int o = t & 63, lg = t >> 6;
  float kbias = bk[hh * 64 + o], vbias = bv[hh * 64 + o];
  float vacc[16];
  const size_t outb = (size_t)bh * NWP_ * 64;
  for (int ls = 0; ls < 16; ++ls) {
    int l = lg * 16 + ls;
    float ka = kbias, va = vbias;
#pragma unroll
    for (int i = 0; i < 64; ++i) {
      float xv = xs[l][i];
      ka = fmaf(xv, wks[o][i], ka);
      va = fmaf(xv, wvs[o][i], va);
    }
    KLP[outb + (size_t)(n0 + l) * 64 + o] = (bf16)ka;
    vacc[ls] = va;
  }
  __syncthreads();
#pragma unroll
  for (int ls = 0; ls < 16; ++ls) wvs[o][lg * 16 + ls] = vacc[ls];
  __syncthreads();
  for (int idx = t; idx < 4096; idx += 256) {
    int oo = idx >> 6, ll = idx & 63;
    VLT[(size_t)bh * 64 * NWP_ + (size_t)oo * NWP_ + n0 + ll] = (bf16)wvs[oo][ll];
  }
}

// ---------------- mask precompute: bit-packed (1 = masked) — R3-verified ----------------
__global__ __launch_bounds__(256) void maskprep(const float* __restrict__ mask,
                                                uint64_t* __restrict__ gm,
                                                uint64_t* __restrict__ wm) {
  int row = blockIdx.x * 4 + (threadIdx.x >> 6);  // b*L + l
  int lane = threadIdx.x & 63;
  if (row >= B_ * L_) return;
  int b = row / L_, l = row % L_;
  const float* mr = mask + (size_t)b * L_ * L_ + (size_t)l * L_;
  for (int w = 0; w < 32; ++w) {
    int m = w * 64 + lane;
    bool masked = (m >= L_) ? true : (mr[m] == 0.0f);
    uint64_t bal = __ballot(masked);
    if (lane == 0) gm[(size_t)row * 32 + w] = bal;
  }
  for (int w = 0; w < 11; ++w) {
    int n = w * 64 + lane;
    bool lmask = true;
    if (n < NW_) {
      float s = mr[3 * n] + mr[3 * n + 1] + mr[3 * n + 2];
      lmask = !(s >= 2.0f);
    }
    uint64_t bal = __ballot(lmask);
    if (lane == 0) wm[(size_t)row * 11 + w] = bal;
  }
}

// ---------------- FUSED global, 16-wave: QK^T -> softmax -> pg + PV (V^T direct) ----------------
// LDS: pool 34.8K + sums 1K
__global__ __launch_bounds__(1024, 4) void attn_gf(const bf16* __restrict__ Q,
    const bf16* __restrict__ K, const bf16* __restrict__ VT,
    const uint64_t* __restrict__ GM,
    float* __restrict__ OP, float* __restrict__ OV) {
  __shared__ float sums[256];
  __shared__ float pool[8704];        // strip 16xSTR (8272) / reduce 8xRW (8704)
  int t = threadIdx.x;
  int lane = t & 63, wave = t >> 6;   // 16 waves
  int lid = lane & 15, g = lane >> 4;
  int q0 = blockIdx.x * 16;
  int bh = blockIdx.y;
  int b = bh >> 3, h = bh & 7;
  const bf16* qb = Q + (size_t)b * L_ * 1024 + h * 64;
  const bf16* kb = K + (size_t)bh * LP_ * 64;
  const bf16* vtg = VT + (size_t)bh * 64 * LP_;
  const uint64_t* gmb = GM + (size_t)b * L_ * 32;

  bf16x8 aq0 = zf8(), aq1 = zf8();
  {
    int qr = q0 + lid;
    if (qr < L_) {
      aq0 = *reinterpret_cast<const bf16x8*>(qb + (size_t)qr * 1024 + g * 8);
      aq1 = *reinterpret_cast<const bf16x8*>(qb + (size_t)qr * 1024 + 32 + g * 8);
    }
  }
  // ---- phase 1: single-pass QK^T, P in registers ----
  uint32_t preg[16];
  float rs[4] = {0.f, 0.f, 0.f, 0.f};
#pragma unroll
  for (int it = 0; it < 4; ++it) {
    int p = it * 16 + wave;
    int c0 = p * 32;
    int col0 = c0 + lid, col1 = c0 + 16 + lid;
    bf16x8 bka0 = *reinterpret_cast<const bf16x8*>(kb + (size_t)col0 * 64 + g * 8);
    bf16x8 bka1 = *reinterpret_cast<const bf16x8*>(kb + (size_t)col0 * 64 + 32 + g * 8);
    bf16x8 bkb0 = *reinterpret_cast<const bf16x8*>(kb + (size_t)col1 * 64 + g * 8);
    bf16x8 bkb1 = *reinterpret_cast<const bf16x8*>(kb + (size_t)col1 * 64 + 32 + g * 8);
    f32x4 acc0 = {0.f, 0.f, 0.f, 0.f}, acc1 = {0.f, 0.f, 0.f, 0.f};
    acc0 = __builtin_amdgcn_mfma_f32_16x16x32_bf16(aq0, bka0, acc0, 0, 0, 0);
    acc0 = __builtin_amdgcn_mfma_f32_16x16x32_bf16(aq1, bka1, acc0, 0, 0, 0);
    acc1 = __builtin_amdgcn_mfma_f32_16x16x32_bf16(aq0, bkb0, acc1, 0, 0, 0);
    acc1 = __builtin_amdgcn_mfma_f32_16x16x32_bf16(aq1, bkb1, acc1, 0, 0, 0);
    int wi = c0 >> 6;
    int bit0 = c0 & 32;
#pragma unroll
    for (int r = 0; r < 4; ++r) {
      int qr = q0 + g * 4 + r;
      uint64_t w = (qr < L_) ? gmb[(size_t)qr * 32 + wi] : ~0ull;
      float pv0 = ((w >> (bit0 + lid)) & 1) ? 0.0f : __expf(acc0[r] * SCALE_);
      float pv1 = ((w >> (bit0 + 16 + lid)) & 1) ? 0.0f : __expf(acc1[r] * SCALE_);
      rs[r] += pv0 + pv1;
      preg[it * 4 + r] = pkbf(pv0, pv1);
    }
  }
#pragma unroll
  for (int off = 8; off >= 1; off >>= 1)
#pragma unroll
    for (int r = 0; r < 4; ++r) rs[r] += __shfl_xor(rs[r], off, 64);
  if (lid == 0) {
#pragma unroll
    for (int r = 0; r < 4; ++r) sums[wave * 16 + g * 4 + r] = rs[r];
  }
  __syncthreads();
  float invr[4];
#pragma unroll
  for (int r = 0; r < 4; ++r) {
    int row = g * 4 + r;
    float s = 0.f;
#pragma unroll
    for (int ww = 0; ww < 16; ++ww) s += sums[ww * 16 + row];
    invr[r] = (s > 0.f) ? 1.0f / s : 0.0f;
  }
  // ---- phase 2: per 16x512 chunk: strip -> pg store + PV ----
  f32x4 vacc[4];
  f32x4 z4 = {0.f, 0.f, 0.f, 0.f};
#pragma unroll
  for (int dg = 0; dg < 4; ++dg) vacc[dg] = z4;
  int qrW = q0 + wave;
  bool rowokW = (qrW < L_);
  const size_t rowbW = (size_t)bh * L_ * L_ + (size_t)(rowokW ? qrW : 0) * L_;
#pragma unroll
  for (int it = 0; it < 4; ++it) {
    int mb0 = it * 512;
#pragma unroll
    for (int r = 0; r < 4; ++r) {
      uint32_t u = preg[it * 4 + r];
      pool[(g * 4 + r) * STR + wave * 32 + lid] = upk_lo(u) * invr[r];
      pool[(g * 4 + r) * STR + wave * 32 + 16 + lid] = upk_hi(u) * invr[r];
    }
    __syncthreads();
    // PV: own-wave 32-col chunk
    bf16x8 af;
#pragma unroll
    for (int e = 0; e < 8; ++e) af[e] = (bf16)pool[lid * STR + wave * 32 + g * 8 + e];
#pragma unroll
    for (int dg = 0; dg < 4; ++dg) {
      bf16x8 bv8 = *reinterpret_cast<const bf16x8*>(vtg + (size_t)(dg * 16 + lid) * LP_ + mb0 + wave * 32 + g * 8);
      vacc[dg] = __builtin_amdgcn_mfma_f32_16x16x32_bf16(af, bv8, vacc[dg], 0, 0, 0);
    }
    // pg store: wave = row, 64 lanes x 2 floats x 4 segs (coalesced, 2-way banks)
    if (rowokW) {
#pragma unroll
      for (int seg = 0; seg < 4; ++seg) {
        int cc = seg * 128 + lane * 2;
        int col = mb0 + cc;
        if (col + 1 < L_) {
          float2 o2 = make_float2(pool[wave * STR + cc], pool[wave * STR + cc + 1]);
          *reinterpret_cast<float2*>(OP + rowbW + col) = o2;
        }
      }
    }
    __syncthreads();
  }
  // ---- cross-wave OV reduce: log tree in pool ----
#pragma unroll
  for (int s = 8; s >= 1; s >>= 1) {
    if (wave >= s && wave < 2 * s) {
#pragma unroll
      for (int dg = 0; dg < 4; ++dg)
#pragma unroll
        for (int r = 0; r < 4; ++r)
          pool[(wave - s) * RW + (g * 4 + r) * RSTR + dg * 16 + lid] = vacc[dg][r];
    }
    __syncthreads();
    if (wave < s) {
#pragma unroll
      for (int dg = 0; dg < 4; ++dg)
#pragma unroll
        for (int r = 0; r < 4; ++r)
          vacc[dg][r] += pool[wave * RW + (g * 4 + r) * RSTR + dg * 16 + lid];
    }
    __syncthreads();
  }
  if (wave == 0) {
    float* ob = OV + (((size_t)b * 16 + h) * L_) * 64;
#pragma unroll
    for (int dg = 0; dg < 4; ++dg)
#pragma unroll
      for (int r = 0; r < 4; ++r) {
        int qr = q0 + g * 4 + r;
        if (qr < L_) ob[(size_t)qr * 64 + dg * 16 + lid] = vacc[dg][r];
      }
  }
}

// ---------------- FUSED local, 16-wave (V^T direct) ----------------
__global__ __launch_bounds__(1024, 4) void attn_lf(const bf16* __restrict__ Q,
    const bf16* __restrict__ K, const bf16* __restrict__ VT,
    const uint64_t* __restrict__ WM,
    float* __restrict__ OP, float* __restrict__ OV) {
  __shared__ float sums[256];
  __shared__ float pool[8704];
  int t = threadIdx.x;
  int lane = t & 63, wave = t >> 6;
  int lid = lane & 15, g = lane >> 4;
  int q0 = blockIdx.x * 16;
  int bh = blockIdx.y;
  int b = bh >> 3, h = bh & 7;
  const bf16* qb = Q + (size_t)b * L_ * 1024 + (8 + h) * 64;
  const bf16* kb = K + (size_t)bh * NWP_ * 64;
  const bf16* vtg = VT + (size_t)bh * 64 * NWP_;
  const uint64_t* wmb = WM + (size_t)b * L_ * 11;

  bf16x8 aq0 = zf8(), aq1 = zf8();
  {
    int qr = q0 + lid;
    if (qr < L_) {
      aq0 = *reinterpret_cast<const bf16x8*>(qb + (size_t)qr * 1024 + g * 8);
      aq1 = *reinterpret_cast<const bf16x8*>(qb + (size_t)qr * 1024 + 32 + g * 8);
    }
  }
  uint32_t preg[8];
  float rs[4] = {0.f, 0.f, 0.f, 0.f};
#pragma unroll
  for (int it = 0; it < 2; ++it) {
    int p = it * 16 + wave;
    if (p < 22) {
      int c0 = p * 32;
      int col0 = c0 + lid, col1 = c0 + 16 + lid;
      bf16x8 bka0 = *reinterpret_cast<const bf16x8*>(kb + (size_t)col0 * 64 + g * 8);
      bf16x8 bka1 = *reinterpret_cast<const bf16x8*>(kb + (size_t)col0 * 64 + 32 + g * 8);
      bf16x8 bkb0 = *reinterpret_cast<const bf16x8*>(kb + (size_t)col1 * 64 + g * 8);
      bf16x8 bkb1 = *reinterpret_cast<const bf16x8*>(kb + (size_t)col1 * 64 + 32 + g * 8);
      f32x4 acc0 = {0.f, 0.f, 0.f, 0.f}, acc1 = {0.f, 0.f, 0.f, 0.f};
      acc0 = __builtin_amdgcn_mfma_f32_16x16x32_bf16(aq0, bka0, acc0, 0, 0, 0);
      acc0 = __builtin_amdgcn_mfma_f32_16x16x32_bf16(aq1, bka1, acc0, 0, 0, 0);
      acc1 = __builtin_amdgcn_mfma_f32_16x16x32_bf16(aq0, bkb0, acc1, 0, 0, 0);
      acc1 = __builtin_amdgcn_mfma_f32_16x16x32_bf16(aq1, bkb1, acc1, 0, 0, 0);
      int wi = c0 >> 6;
      int bit0 = c0 & 32;
#pragma unroll
      for (int r = 0; r < 4; ++r) {
        int qr = q0 + g * 4 + r;
        uint64_t w = (qr < L_) ? wmb[(size_t)qr * 11 + wi] : ~0ull;
        float pv0 = ((w >> (bit0 + lid)) & 1) ? 0.0f : __expf(acc0[r] * SCALE_);
        float pv1 = ((w >> (bit0 + 16 + lid)) & 1) ? 0.0f : __expf(acc1[r] * SCALE_);
        rs[r] += pv0 + pv1;
        preg[it * 4 + r] = pkbf(pv0, pv1);
      }
    }
  }
#pragma unroll
  for (int off = 8; off >= 1; off >>= 1)
#pragma unroll
    for (int r = 0; r < 4; ++r) rs[r] += __shfl_xor(rs[r], off, 64);
  if (lid == 0) {
#pragma unroll
    for (int r = 0; r < 4; ++r) sums[wave * 16 + g * 4 + r] = rs[r];
  }
  __syncthreads();
  float invr[4];
#pragma unroll
  for (int r = 0; r < 4; ++r) {
    int row = g * 4 + r;
    float s = 0.f;
#pragma unroll
    for (int ww = 0; ww < 16; ++ww) s += sums[ww * 16 + row];
    invr[r] = (s > 0.f) ? 1.0f / s : 0.0f;
  }
  f32x4 vacc[4];
  f32x4 z4 = {0.f, 0.f, 0.f, 0.f};
#pragma unroll
  for (int dg = 0; dg < 4; ++dg) vacc[dg] = z4;
  int qrW = q0 + wave;
  bool rowokW = (qrW < L_);
  const size_t rowbW = (size_t)bh * L_ * NW_ + (size_t)(rowokW ? qrW : 0) * NW_;
#pragma unroll
  for (int it = 0; it < 2; ++it) {
    int p = it * 16 + wave;
    bool act = (p < 22);
    int mb0 = it * 512;
    if (act) {
#pragma unroll
      for (int r = 0; r < 4; ++r) {
        uint32_t u = preg[it * 4 + r];
        pool[(g * 4 + r) * STR + wave * 32 + lid] = upk_lo(u) * invr[r];
        pool[(g * 4 + r) * STR + wave * 32 + 16 + lid] = upk_hi(u) * invr[r];
      }
    }
    __syncthreads();
    if (act) {
      bf16x8 af;
#pragma unroll
      for (int e = 0; e < 8; ++e) af[e] = (bf16)pool[lid * STR + wave * 32 + g * 8 + e];
#pragma unroll
      for (int dg = 0; dg < 4; ++dg) {
        bf16x8 bv8 = *reinterpret_cast<const bf16x8*>(vtg + (size_t)(dg * 16 + lid) * NWP_ + mb0 + wave * 32 + g * 8);
        vacc[dg] = __builtin_amdgcn_mfma_f32_16x16x32_bf16(af, bv8, vacc[dg], 0, 0, 0);
      }
    }
    if (rowokW) {
#pragma unroll
      for (int seg = 0; seg < 4; ++seg) {
        int cc = seg * 128 + lane * 2;
        int col = mb0 + cc;
        if (col + 1 < NW_) {
          float2 o2 = make_float2(pool[wave * STR + cc], pool[wave * STR + cc + 1]);
          *reinterpret_cast<float2*>(OP + rowbW + col) = o2;
        }
      }
    }
    __syncthreads();
  }
#pragma unroll
  for (int s = 8; s >= 1; s >>= 1) {
    if (wave >= s && wave < 2 * s) {
#pragma unroll
      for (int dg = 0; dg < 4; ++dg)
#pragma unroll
        for (int r = 0; r < 4; ++r)
          pool[(wave - s) * RW + (g * 4 + r) * RSTR + dg * 16 + lid] = vacc[dg][r];
    }
    __syncthreads();
    if (wave < s) {
#pragma unroll
      for (int dg = 0; dg < 4; ++dg)
#pragma unroll
        for (int r = 0; r < 4; ++r)
          vacc[dg][r] += pool[wave * RW + (g * 4 + r) * RSTR + dg * 16 + lid];
    }
    __syncthreads();
  }
  if (wave == 0) {
    float* ob = OV + (((size_t)b * 16 + 8 + h) * L_) * 64;
#pragma unroll
    for (int dg = 0; dg < 4; ++dg)
#pragma unroll
      for (int r = 0; r < 4; ++r) {
        int qr = q0 + g * 4 + r;
        if (qr < L_) ob[(size_t)qr * 64 + dg * 16 + lid] = vacc[dg][r];
      }
  }
}

extern "C" void kernel_launch(void* const* d_in, const int* in_sizes, int n_in,
                              void* d_out, int out_size, void* d_ws, size_t ws_size,
                              hipStream_t stream) {
  (void)in_sizes; (void)n_in; (void)out_size; (void)ws_size;
  const float* x    = (const float*)d_in[0];
  const float* mask = (const float*)d_in[1];
  const float* Wq   = (const float*)d_in[2];
  const float* bq   = (const float*)d_in[3];
  const float* Wk   = (const float*)d_in[4];
  const float* bk   = (const float*)d_in[5];
  const float* Wv   = (const float*)d_in[6];
  const float* bv   = (const float*)d_in[7];

  char* ws = (char*)d_ws;
  bf16* qbb     = (bf16*)(ws + 0);            // 8,380,416
  bf16* kgb     = (bf16*)(ws + 8380416);      // 4,194,304
  bf16* vgT     = (bf16*)(ws + 12574720);     // 4,194,304 (V^T [bh][d][m])
  bf16* klb     = (bf16*)(ws + 16769024);     // 1,441,792
  bf16* vlT     = (bf16*)(ws + 18210816);     // 1,441,792 (V^T local)
  uint64_t* gm  = (uint64_t*)(ws + 19652608); // 1,047,552
  uint64_t* wm  = (uint64_t*)(ws + 20700160); // 360,096
  bf16* xbb     = (bf16*)(ws + 21060256);     // 8,380,416 (x in bf16)
  bf16* wqb     = (bf16*)(ws + 29440672);     // 2,097,152 (Wq in bf16)

  float* out    = (float*)d_out;
  float* o_vall = out;                 // (2,16,2046,64)
  float* o_pg   = out + 4190208;       // (2,8,2046,2046)
  float* o_pl   = out + 71168064;      // (2,8,2046,682)

  cast4<<<4092, 256, 0, stream>>>(x, xbb, 4190208);
  cast4<<<1024, 256, 0, stream>>>(Wq, wqb, 1048576);
  qgemm_t<<<dim3(64, 8), 256, 0, stream>>>(xbb, wqb, bq, qbb);
  proj_g32<<<dim3(32, 16), 256, 0, stream>>>(x, Wk, bk, Wv, bv, kgb, vgT);
  proj_l32<<<dim3(11, 16), 256, 0, stream>>>(x, Wk, bk, Wv, bv, klb, vlT);
  maskprep<<<1023, 256, 0, stream>>>(mask, gm, wm);

  attn_gf<<<dim3(128, 16), 1024, 0, stream>>>(qbb, kgb, vgT, gm, o_pg, o_vall);
  attn_lf<<<dim3(128, 16), 1024, 0, stream>>>(qbb, klb, vlT, wm, o_pl, o_vall);
}

// Round 19
// 353.544 us; speedup vs baseline: 1.1443x; 1.0935x over previous
//
#include <hip/hip_runtime.h>
#include <hip/hip_bf16.h>
#include <stdint.h>

typedef __bf16 bf16;
typedef bf16 bf16x8 __attribute__((ext_vector_type(8)));
typedef float f32x4 __attribute__((ext_vector_type(4)));
typedef float f32x2 __attribute__((ext_vector_type(2)));

#define B_ 2
#define L_ 2046
#define H_ 16
#define NW_ 682
#define LP_ 2048
#define NWP_ 704
#define M_ (B_*L_)
#define SCALE_ 0.125f
#define STR 517        // strip row stride (f32): odd -> <=2-way LDS banks
#define RSTR 68        // reduce-tree d stride
#define RW (16*RSTR)   // reduce-tree per-wave block

__device__ inline bf16x8 zf8() {
  bf16x8 v;
#pragma unroll
  for (int e = 0; e < 8; ++e) v[e] = (bf16)0.0f;
  return v;
}

__device__ inline uint32_t pkbf(float a, float b) {
  uint16_t ua = __builtin_bit_cast(uint16_t, (bf16)a);
  uint16_t ub = __builtin_bit_cast(uint16_t, (bf16)b);
  return (uint32_t)ua | ((uint32_t)ub << 16);
}
__device__ inline float upk_lo(uint32_t u) { return __builtin_bit_cast(float, u << 16); }
__device__ inline float upk_hi(uint32_t u) { return __builtin_bit_cast(float, u & 0xffff0000u); }

// streaming store (nt): output is write-once, never re-read -> keep out of L2
__device__ inline void st_nt2(float* p, float a, float b) {
  f32x2 v; v[0] = a; v[1] = b;
  __builtin_nontemporal_store(v, reinterpret_cast<f32x2*>(p));
}

// ---------------- cast f32 -> bf16 (vectorized x4) ----------------
__global__ __launch_bounds__(256) void cast4(const float* __restrict__ in,
                                             bf16* __restrict__ out, int n) {
  int i = (blockIdx.x * 256 + threadIdx.x) * 4;
  if (i + 3 < n) {
    float4 v = *reinterpret_cast<const float4*>(in + i);
    bf16 tmp[4];
    tmp[0] = (bf16)v.x; tmp[1] = (bf16)v.y; tmp[2] = (bf16)v.z; tmp[3] = (bf16)v.w;
    *reinterpret_cast<uint64_t*>(out + i) = *reinterpret_cast<const uint64_t*>(tmp);
  } else {
    for (; i < n; ++i) out[i] = (bf16)in[i];
  }
}

// ---------------- q = x @ Wq^T + bq : LDS-tiled MFMA GEMM (64x128 tile, BK=32) ----------------
__global__ __launch_bounds__(256) void qgemm_t(const bf16* __restrict__ X,
                                               const bf16* __restrict__ W,
                                               const float* __restrict__ bq,
                                               bf16* __restrict__ Q) {
  __shared__ bf16 As[64 * 40];
  __shared__ bf16 Bs[128 * 40];
  int t = threadIdx.x, lane = t & 63, w = t >> 6;
  int lid = lane & 15, g = lane >> 4;
  int m0 = blockIdx.x * 64, n0 = blockIdx.y * 128;
  int wm = (w >> 1) * 32, wn = (w & 1) * 64;
  f32x4 z4 = {0.f, 0.f, 0.f, 0.f};
  f32x4 acc[2][4];
#pragma unroll
  for (int mi = 0; mi < 2; ++mi)
#pragma unroll
    for (int ni = 0; ni < 4; ++ni) acc[mi][ni] = z4;
  int r1 = t >> 2, c1 = t & 3;
  for (int k0 = 0; k0 < 1024; k0 += 32) {
    int ga = m0 + r1; if (ga >= M_) ga = M_ - 1;
    bf16x8 av = *reinterpret_cast<const bf16x8*>(X + (size_t)ga * 1024 + k0 + c1 * 8);
    bf16x8 bv1 = *reinterpret_cast<const bf16x8*>(W + (size_t)(n0 + r1) * 1024 + k0 + c1 * 8);
    bf16x8 bv2 = *reinterpret_cast<const bf16x8*>(W + (size_t)(n0 + 64 + r1) * 1024 + k0 + c1 * 8);
    __syncthreads();
    *reinterpret_cast<bf16x8*>(As + r1 * 40 + c1 * 8) = av;
    *reinterpret_cast<bf16x8*>(Bs + r1 * 40 + c1 * 8) = bv1;
    *reinterpret_cast<bf16x8*>(Bs + (64 + r1) * 40 + c1 * 8) = bv2;
    __syncthreads();
    bf16x8 af[2], bfr[4];
#pragma unroll
    for (int mi = 0; mi < 2; ++mi)
      af[mi] = *reinterpret_cast<const bf16x8*>(As + (wm + mi * 16 + lid) * 40 + g * 8);
#pragma unroll
    for (int ni = 0; ni < 4; ++ni)
      bfr[ni] = *reinterpret_cast<const bf16x8*>(Bs + (wn + ni * 16 + lid) * 40 + g * 8);
#pragma unroll
    for (int mi = 0; mi < 2; ++mi)
#pragma unroll
      for (int ni = 0; ni < 4; ++ni)
        acc[mi][ni] = __builtin_amdgcn_mfma_f32_16x16x32_bf16(af[mi], bfr[ni], acc[mi][ni], 0, 0, 0);
  }
  float bias[4];
#pragma unroll
  for (int ni = 0; ni < 4; ++ni) bias[ni] = bq[n0 + wn + ni * 16 + lid];
#pragma unroll
  for (int mi = 0; mi < 2; ++mi)
#pragma unroll
    for (int r = 0; r < 4; ++r) {
      int row = m0 + wm + mi * 16 + g * 4 + r;
      if (row < M_) {
#pragma unroll
        for (int ni = 0; ni < 4; ++ni)
          Q[(size_t)row * 1024 + n0 + wn + ni * 16 + lid] = (bf16)(acc[mi][ni][r] + bias[ni]);
      }
    }
}

// ---------------- global-head K/V projections; K row-major, V TRANSPOSED out ----------------
__global__ __launch_bounds__(256) void proj_g32(const float* __restrict__ x,
    const float* __restrict__ Wk, const float* __restrict__ bk,
    const float* __restrict__ Wv, const float* __restrict__ bv,
    bf16* __restrict__ KGP, bf16* __restrict__ VGT) {
  __shared__ float xs[64][64];
  __shared__ float wks[64][65];
  __shared__ float wvs[64][65];
  int t = threadIdx.x;
  int lb = blockIdx.x, bh = blockIdx.y;
  int b = bh >> 3, h = bh & 7;
  int l0 = lb * 64;
  for (int idx = t; idx < 4096; idx += 256) {
    int r = idx >> 6, c = idx & 63;
    int l = l0 + r;
    xs[r][c] = (l < L_) ? x[((size_t)b * L_ + l) * 1024 + h * 64 + c] : 0.0f;
    wks[r][c] = Wk[(size_t)h * 4096 + idx];
    wvs[r][c] = Wv[(size_t)h * 4096 + idx];
  }
  __syncthreads();
  int o = t & 63, lg = t >> 6;
  float kbias = bk[h * 64 + o], vbias = bv[h * 64 + o];
  float vacc[16];
  const size_t outb = (size_t)bh * LP_ * 64;
  for (int ls = 0; ls < 16; ++ls) {
    int l = lg * 16 + ls;
    float ka = kbias, va = vbias;
#pragma unroll
    for (int i = 0; i < 64; ++i) {
      float xv = xs[l][i];
      ka = fmaf(xv, wks[o][i], ka);
      va = fmaf(xv, wvs[o][i], va);
    }
    KGP[outb + (size_t)(l0 + l) * 64 + o] = (bf16)ka;
    vacc[ls] = va;
  }
  __syncthreads();
#pragma unroll
  for (int ls = 0; ls < 16; ++ls) wvs[o][lg * 16 + ls] = vacc[ls];
  __syncthreads();
  for (int idx = t; idx < 4096; idx += 256) {
    int oo = idx >> 6, ll = idx & 63;
    VGT[(size_t)bh * 64 * LP_ + (size_t)oo * LP_ + l0 + ll] = (bf16)wvs[oo][ll];
  }
}

// ---------------- local-head window-avg + K/V projections; V TRANSPOSED out ----------------
__global__ __launch_bounds__(256) void proj_l32(const float* __restrict__ x,
    const float* __restrict__ Wk, const float* __restrict__ bk,
    const float* __restrict__ Wv, const float* __restrict__ bv,
    bf16* __restrict__ KLP, bf16* __restrict__ VLT) {
  __shared__ float xs[64][64];
  __shared__ float wks[64][65];
  __shared__ float wvs[64][65];
  int t = threadIdx.x;
  int nb = blockIdx.x, bh = blockIdx.y;
  int b = bh >> 3, h = bh & 7;
  int n0 = nb * 64;
  int hh = 8 + h;
  for (int idx = t; idx < 4096; idx += 256) {
    int r = idx >> 6, c = idx & 63;
    int n = n0 + r;
    float v = 0.0f;
    if (n < NW_) {
      size_t base = ((size_t)b * L_ + 3 * n) * 1024 + hh * 64 + c;
      v = (x[base] + x[base + 1024] + x[base + 2048]) * (1.0f / 3.0f);
    }
    xs[r][c] = v;
    wks[r][c] = Wk[(size_t)hh * 4096 + idx];
    wvs[r][c] = Wv[(size_t)hh * 4096 + idx];
  }
  __syncthreads();
  int o = t & 63, lg = t >> 6;
  float kbias = bk[hh * 64 + o], vbias = bv[hh * 64 + o];
  float vacc[16];
  const size_t outb = (size_t)bh * NWP_ * 64;
  for (int ls = 0; ls < 16; ++ls) {
    int l = lg * 16 + ls;
    float ka = kbias, va = vbias;
#pragma unroll
    for (int i = 0; i < 64; ++i) {
      float xv = xs[l][i];
      ka = fmaf(xv, wks[o][i], ka);
      va = fmaf(xv, wvs[o][i], va);
    }
    KLP[outb + (size_t)(n0 + l) * 64 + o] = (bf16)ka;
    vacc[ls] = va;
  }
  __syncthreads();
#pragma unroll
  for (int ls = 0; ls < 16; ++ls) wvs[o][lg * 16 + ls] = vacc[ls];
  __syncthreads();
  for (int idx = t; idx < 4096; idx += 256) {
    int oo = idx >> 6, ll = idx & 63;
    VLT[(size_t)bh * 64 * NWP_ + (size_t)oo * NWP_ + n0 + ll] = (bf16)wvs[oo][ll];
  }
}

// ---------------- mask precompute: bit-packed (1 = masked) — R3-verified ----------------
__global__ __launch_bounds__(256) void maskprep(const float* __restrict__ mask,
                                                uint64_t* __restrict__ gm,
                                                uint64_t* __restrict__ wm) {
  int row = blockIdx.x * 4 + (threadIdx.x >> 6);  // b*L + l
  int lane = threadIdx.x & 63;
  if (row >= B_ * L_) return;
  int b = row / L_, l = row % L_;
  const float* mr = mask + (size_t)b * L_ * L_ + (size_t)l * L_;
  for (int w = 0; w < 32; ++w) {
    int m = w * 64 + lane;
    bool masked = (m >= L_) ? true : (mr[m] == 0.0f);
    uint64_t bal = __ballot(masked);
    if (lane == 0) gm[(size_t)row * 32 + w] = bal;
  }
  for (int w = 0; w < 11; ++w) {
    int n = w * 64 + lane;
    bool lmask = true;
    if (n < NW_) {
      float s = mr[3 * n] + mr[3 * n + 1] + mr[3 * n + 2];
      lmask = !(s >= 2.0f);
    }
    uint64_t bal = __ballot(lmask);
    if (lane == 0) wm[(size_t)row * 11 + w] = bal;
  }
}

// ---------------- FUSED global, 16-wave: QK^T -> softmax -> pg + PV (V^T direct) ----------------
__global__ __launch_bounds__(1024, 4) void attn_gf(const bf16* __restrict__ Q,
    const bf16* __restrict__ K, const bf16* __restrict__ VT,
    const uint64_t* __restrict__ GM,
    float* __restrict__ OP, float* __restrict__ OV) {
  __shared__ float sums[256];
  __shared__ float pool[8704];
  int t = threadIdx.x;
  int lane = t & 63, wave = t >> 6;   // 16 waves
  int lid = lane & 15, g = lane >> 4;
  int q0 = blockIdx.x * 16;
  int bh = blockIdx.y;
  int b = bh >> 3, h = bh & 7;
  const bf16* qb = Q + (size_t)b * L_ * 1024 + h * 64;
  const bf16* kb = K + (size_t)bh * LP_ * 64;
  const bf16* vtg = VT + (size_t)bh * 64 * LP_;
  const uint64_t* gmb = GM + (size_t)b * L_ * 32;

  bf16x8 aq0 = zf8(), aq1 = zf8();
  {
    int qr = q0 + lid;
    if (qr < L_) {
      aq0 = *reinterpret_cast<const bf16x8*>(qb + (size_t)qr * 1024 + g * 8);
      aq1 = *reinterpret_cast<const bf16x8*>(qb + (size_t)qr * 1024 + 32 + g * 8);
    }
  }
  // ---- phase 1: single-pass QK^T, P in registers ----
  uint32_t preg[16];
  float rs[4] = {0.f, 0.f, 0.f, 0.f};
#pragma unroll
  for (int it = 0; it < 4; ++it) {
    int p = it * 16 + wave;
    int c0 = p * 32;
    int col0 = c0 + lid, col1 = c0 + 16 + lid;
    bf16x8 bka0 = *reinterpret_cast<const bf16x8*>(kb + (size_t)col0 * 64 + g * 8);
    bf16x8 bka1 = *reinterpret_cast<const bf16x8*>(kb + (size_t)col0 * 64 + 32 + g * 8);
    bf16x8 bkb0 = *reinterpret_cast<const bf16x8*>(kb + (size_t)col1 * 64 + g * 8);
    bf16x8 bkb1 = *reinterpret_cast<const bf16x8*>(kb + (size_t)col1 * 64 + 32 + g * 8);
    f32x4 acc0 = {0.f, 0.f, 0.f, 0.f}, acc1 = {0.f, 0.f, 0.f, 0.f};
    acc0 = __builtin_amdgcn_mfma_f32_16x16x32_bf16(aq0, bka0, acc0, 0, 0, 0);
    acc0 = __builtin_amdgcn_mfma_f32_16x16x32_bf16(aq1, bka1, acc0, 0, 0, 0);
    acc1 = __builtin_amdgcn_mfma_f32_16x16x32_bf16(aq0, bkb0, acc1, 0, 0, 0);
    acc1 = __builtin_amdgcn_mfma_f32_16x16x32_bf16(aq1, bkb1, acc1, 0, 0, 0);
    int wi = c0 >> 6;
    int bit0 = c0 & 32;
#pragma unroll
    for (int r = 0; r < 4; ++r) {
      int qr = q0 + g * 4 + r;
      uint64_t w = (qr < L_) ? gmb[(size_t)qr * 32 + wi] : ~0ull;
      float pv0 = ((w >> (bit0 + lid)) & 1) ? 0.0f : __expf(acc0[r] * SCALE_);
      float pv1 = ((w >> (bit0 + 16 + lid)) & 1) ? 0.0f : __expf(acc1[r] * SCALE_);
      rs[r] += pv0 + pv1;
      preg[it * 4 + r] = pkbf(pv0, pv1);
    }
  }
#pragma unroll
  for (int off = 8; off >= 1; off >>= 1)
#pragma unroll
    for (int r = 0; r < 4; ++r) rs[r] += __shfl_xor(rs[r], off, 64);
  if (lid == 0) {
#pragma unroll
    for (int r = 0; r < 4; ++r) sums[wave * 16 + g * 4 + r] = rs[r];
  }
  __syncthreads();
  float invr[4];
#pragma unroll
  for (int r = 0; r < 4; ++r) {
    int row = g * 4 + r;
    float s = 0.f;
#pragma unroll
    for (int ww = 0; ww < 16; ++ww) s += sums[ww * 16 + row];
    invr[r] = (s > 0.f) ? 1.0f / s : 0.0f;
  }
  // ---- phase 2: per 16x512 chunk: strip -> pg store (nt) + PV ----
  f32x4 vacc[4];
  f32x4 z4 = {0.f, 0.f, 0.f, 0.f};
#pragma unroll
  for (int dg = 0; dg < 4; ++dg) vacc[dg] = z4;
  int qrW = q0 + wave;
  bool rowokW = (qrW < L_);
  const size_t rowbW = (size_t)bh * L_ * L_ + (size_t)(rowokW ? qrW : 0) * L_;
#pragma unroll
  for (int it = 0; it < 4; ++it) {
    int mb0 = it * 512;
#pragma unroll
    for (int r = 0; r < 4; ++r) {
      uint32_t u = preg[it * 4 + r];
      pool[(g * 4 + r) * STR + wave * 32 + lid] = upk_lo(u) * invr[r];
      pool[(g * 4 + r) * STR + wave * 32 + 16 + lid] = upk_hi(u) * invr[r];
    }
    __syncthreads();
    bf16x8 af;
#pragma unroll
    for (int e = 0; e < 8; ++e) af[e] = (bf16)pool[lid * STR + wave * 32 + g * 8 + e];
#pragma unroll
    for (int dg = 0; dg < 4; ++dg) {
      bf16x8 bv8 = *reinterpret_cast<const bf16x8*>(vtg + (size_t)(dg * 16 + lid) * LP_ + mb0 + wave * 32 + g * 8);
      vacc[dg] = __builtin_amdgcn_mfma_f32_16x16x32_bf16(af, bv8, vacc[dg], 0, 0, 0);
    }
    if (rowokW) {
#pragma unroll
      for (int seg = 0; seg < 4; ++seg) {
        int cc = seg * 128 + lane * 2;
        int col = mb0 + cc;
        if (col + 1 < L_)
          st_nt2(OP + rowbW + col, pool[wave * STR + cc], pool[wave * STR + cc + 1]);
      }
    }
    __syncthreads();
  }
  // ---- cross-wave OV reduce: log tree in pool ----
#pragma unroll
  for (int s = 8; s >= 1; s >>= 1) {
    if (wave >= s && wave < 2 * s) {
#pragma unroll
      for (int dg = 0; dg < 4; ++dg)
#pragma unroll
        for (int r = 0; r < 4; ++r)
          pool[(wave - s) * RW + (g * 4 + r) * RSTR + dg * 16 + lid] = vacc[dg][r];
    }
    __syncthreads();
    if (wave < s) {
#pragma unroll
      for (int dg = 0; dg < 4; ++dg)
#pragma unroll
        for (int r = 0; r < 4; ++r)
          vacc[dg][r] += pool[wave * RW + (g * 4 + r) * RSTR + dg * 16 + lid];
    }
    __syncthreads();
  }
  if (wave == 0) {
    float* ob = OV + (((size_t)b * 16 + h) * L_) * 64;
#pragma unroll
    for (int dg = 0; dg < 4; ++dg)
#pragma unroll
      for (int r = 0; r < 4; ++r) {
        int qr = q0 + g * 4 + r;
        if (qr < L_) __builtin_nontemporal_store(vacc[dg][r], ob + (size_t)qr * 64 + dg * 16 + lid);
      }
  }
}

// ---------------- FUSED local, 16-wave (V^T direct) ----------------
__global__ __launch_bounds__(1024, 4) void attn_lf(const bf16* __restrict__ Q,
    const bf16* __restrict__ K, const bf16* __restrict__ VT,
    const uint64_t* __restrict__ WM,
    float* __restrict__ OP, float* __restrict__ OV) {
  __shared__ float sums[256];
  __shared__ float pool[8704];
  int t = threadIdx.x;
  int lane = t & 63, wave = t >> 6;
  int lid = lane & 15, g = lane >> 4;
  int q0 = blockIdx.x * 16;
  int bh = blockIdx.y;
  int b = bh >> 3, h = bh & 7;
  const bf16* qb = Q + (size_t)b * L_ * 1024 + (8 + h) * 64;
  const bf16* kb = K + (size_t)bh * NWP_ * 64;
  const bf16* vtg = VT + (size_t)bh * 64 * NWP_;
  const uint64_t* wmb = WM + (size_t)b * L_ * 11;

  bf16x8 aq0 = zf8(), aq1 = zf8();
  {
    int qr = q0 + lid;
    if (qr < L_) {
      aq0 = *reinterpret_cast<const bf16x8*>(qb + (size_t)qr * 1024 + g * 8);
      aq1 = *reinterpret_cast<const bf16x8*>(qb + (size_t)qr * 1024 + 32 + g * 8);
    }
  }
  uint32_t preg[8];
  float rs[4] = {0.f, 0.f, 0.f, 0.f};
#pragma unroll
  for (int it = 0; it < 2; ++it) {
    int p = it * 16 + wave;
    if (p < 22) {
      int c0 = p * 32;
      int col0 = c0 + lid, col1 = c0 + 16 + lid;
      bf16x8 bka0 = *reinterpret_cast<const bf16x8*>(kb + (size_t)col0 * 64 + g * 8);
      bf16x8 bka1 = *reinterpret_cast<const bf16x8*>(kb + (size_t)col0 * 64 + 32 + g * 8);
      bf16x8 bkb0 = *reinterpret_cast<const bf16x8*>(kb + (size_t)col1 * 64 + g * 8);
      bf16x8 bkb1 = *reinterpret_cast<const bf16x8*>(kb + (size_t)col1 * 64 + 32 + g * 8);
      f32x4 acc0 = {0.f, 0.f, 0.f, 0.f}, acc1 = {0.f, 0.f, 0.f, 0.f};
      acc0 = __builtin_amdgcn_mfma_f32_16x16x32_bf16(aq0, bka0, acc0, 0, 0, 0);
      acc0 = __builtin_amdgcn_mfma_f32_16x16x32_bf16(aq1, bka1, acc0, 0, 0, 0);
      acc1 = __builtin_amdgcn_mfma_f32_16x16x32_bf16(aq0, bkb0, acc1, 0, 0, 0);
      acc1 = __builtin_amdgcn_mfma_f32_16x16x32_bf16(aq1, bkb1, acc1, 0, 0, 0);
      int wi = c0 >> 6;
      int bit0 = c0 & 32;
#pragma unroll
      for (int r = 0; r < 4; ++r) {
        int qr = q0 + g * 4 + r;
        uint64_t w = (qr < L_) ? wmb[(size_t)qr * 11 + wi] : ~0ull;
        float pv0 = ((w >> (bit0 + lid)) & 1) ? 0.0f : __expf(acc0[r] * SCALE_);
        float pv1 = ((w >> (bit0 + 16 + lid)) & 1) ? 0.0f : __expf(acc1[r] * SCALE_);
        rs[r] += pv0 + pv1;
        preg[it * 4 + r] = pkbf(pv0, pv1);
      }
    }
  }
#pragma unroll
  for (int off = 8; off >= 1; off >>= 1)
#pragma unroll
    for (int r = 0; r < 4; ++r) rs[r] += __shfl_xor(rs[r], off, 64);
  if (lid == 0) {
#pragma unroll
    for (int r = 0; r < 4; ++r) sums[wave * 16 + g * 4 + r] = rs[r];
  }
  __syncthreads();
  float invr[4];
#pragma unroll
  for (int r = 0; r < 4; ++r) {
    int row = g * 4 + r;
    float s = 0.f;
#pragma unroll
    for (int ww = 0; ww < 16; ++ww) s += sums[ww * 16 + row];
    invr[r] = (s > 0.f) ? 1.0f / s : 0.0f;
  }
  f32x4 vacc[4];
  f32x4 z4 = {0.f, 0.f, 0.f, 0.f};
#pragma unroll
  for (int dg = 0; dg < 4; ++dg) vacc[dg] = z4;
  int qrW = q0 + wave;
  bool rowokW = (qrW < L_);
  const size_t rowbW = (size_t)bh * L_ * NW_ + (size_t)(rowokW ? qrW : 0) * NW_;
#pragma unroll
  for (int it = 0; it < 2; ++it) {
    int p = it * 16 + wave;
    bool act = (p < 22);
    int mb0 = it * 512;
    if (act) {
#pragma unroll
      for (int r = 0; r < 4; ++r) {
        uint32_t u = preg[it * 4 + r];
        pool[(g * 4 + r) * STR + wave * 32 + lid] = upk_lo(u) * invr[r];
        pool[(g * 4 + r) * STR + wave * 32 + 16 + lid] = upk_hi(u) * invr[r];
      }
    }
    __syncthreads();
    if (act) {
      bf16x8 af;
#pragma unroll
      for (int e = 0; e < 8; ++e) af[e] = (bf16)pool[lid * STR + wave * 32 + g * 8 + e];
#pragma unroll
      for (int dg = 0; dg < 4; ++dg) {
        bf16x8 bv8 = *reinterpret_cast<const bf16x8*>(vtg + (size_t)(dg * 16 + lid) * NWP_ + mb0 + wave * 32 + g * 8);
        vacc[dg] = __builtin_amdgcn_mfma_f32_16x16x32_bf16(af, bv8, vacc[dg], 0, 0, 0);
      }
    }
    if (rowokW) {
#pragma unroll
      for (int seg = 0; seg < 4; ++seg) {
        int cc = seg * 128 + lane * 2;
        int col = mb0 + cc;
        if (col + 1 < NW_)
          st_nt2(OP + rowbW + col, pool[wave * STR + cc], pool[wave * STR + cc + 1]);
      }
    }
    __syncthreads();
  }
#pragma unroll
  for (int s = 8; s >= 1; s >>= 1) {
    if (wave >= s && wave < 2 * s) {
#pragma unroll
      for (int dg = 0; dg < 4; ++dg)
#pragma unroll
        for (int r = 0; r < 4; ++r)
          pool[(wave - s) * RW + (g * 4 + r) * RSTR + dg * 16 + lid] = vacc[dg][r];
    }
    __syncthreads();
    if (wave < s) {
#pragma unroll
      for (int dg = 0; dg < 4; ++dg)
#pragma unroll
        for (int r = 0; r < 4; ++r)
          vacc[dg][r] += pool[wave * RW + (g * 4 + r) * RSTR + dg * 16 + lid];
    }
    __syncthreads();
  }
  if (wave == 0) {
    float* ob = OV + (((size_t)b * 16 + 8 + h) * L_) * 64;
#pragma unroll
    for (int dg = 0; dg < 4; ++dg)
#pragma unroll
      for (int r = 0; r < 4; ++r) {
        int qr = q0 + g * 4 + r;
        if (qr < L_) __builtin_nontemporal_store(vacc[dg][r], ob + (size_t)qr * 64 + dg * 16 + lid);
      }
  }
}

extern "C" void kernel_launch(void* const* d_in, const int* in_sizes, int n_in,
                              void* d_out, int out_size, void* d_ws, size_t ws_size,
                              hipStream_t stream) {
  (void)in_sizes; (void)n_in; (void)out_size; (void)ws_size;
  const float* x    = (const float*)d_in[0];
  const float* mask = (const float*)d_in[1];
  const float* Wq   = (const float*)d_in[2];
  const float* bq   = (const float*)d_in[3];
  const float* Wk   = (const float*)d_in[4];
  const float* bk   = (const float*)d_in[5];
  const float* Wv   = (const float*)d_in[6];
  const float* bv   = (const float*)d_in[7];

  char* ws = (char*)d_ws;
  bf16* qbb     = (bf16*)(ws + 0);            // 8,380,416
  bf16* kgb     = (bf16*)(ws + 8380416);      // 4,194,304
  bf16* vgT     = (bf16*)(ws + 12574720);     // 4,194,304 (V^T [bh][d][m])
  bf16* klb     = (bf16*)(ws + 16769024);     // 1,441,792
  bf16* vlT     = (bf16*)(ws + 18210816);     // 1,441,792 (V^T local)
  uint64_t* gm  = (uint64_t*)(ws + 19652608); // 1,047,552
  uint64_t* wm  = (uint64_t*)(ws + 20700160); // 360,096
  bf16* xbb     = (bf16*)(ws + 21060256);     // 8,380,416 (x in bf16)
  bf16* wqb     = (bf16*)(ws + 29440672);     // 2,097,152 (Wq in bf16)

  float* out    = (float*)d_out;
  float* o_vall = out;                 // (2,16,2046,64)
  float* o_pg   = out + 4190208;       // (2,8,2046,2046)
  float* o_pl   = out + 71168064;      // (2,8,2046,682)

  cast4<<<4092, 256, 0, stream>>>(x, xbb, 4190208);
  cast4<<<1024, 256, 0, stream>>>(Wq, wqb, 1048576);
  qgemm_t<<<dim3(64, 8), 256, 0, stream>>>(xbb, wqb, bq, qbb);
  proj_g32<<<dim3(32, 16), 256, 0, stream>>>(x, Wk, bk, Wv, bv, kgb, vgT);
  proj_l32<<<dim3(11, 16), 256, 0, stream>>>(x, Wk, bk, Wv, bv, klb, vlT);
  maskprep<<<1023, 256, 0, stream>>>(mask, gm, wm);

  attn_gf<<<dim3(128, 16), 1024, 0, stream>>>(qbb, kgb, vgT, gm, o_pg, o_vall);
  attn_lf<<<dim3(128, 16), 1024, 0, stream>>>(qbb, klb, vlT, wm, o_pl, o_vall);
}

// Round 20
// 349.977 us; speedup vs baseline: 1.1560x; 1.0102x over previous
//
#include <hip/hip_runtime.h>
#include <hip/hip_bf16.h>
#include <stdint.h>

typedef __bf16 bf16;
typedef bf16 bf16x8 __attribute__((ext_vector_type(8)));
typedef float f32x4 __attribute__((ext_vector_type(4)));
typedef float f32x2 __attribute__((ext_vector_type(2)));

#define B_ 2
#define L_ 2046
#define H_ 16
#define NW_ 682
#define LP_ 2048
#define NWP_ 704
#define M_ (B_*L_)
#define SCALE_ 0.125f
#define STR 517        // strip row stride (f32): odd -> <=2-way LDS banks
#define RSTR 68        // reduce-tree d stride
#define RW (16*RSTR)   // reduce-tree per-wave block

__device__ inline bf16x8 zf8() {
  bf16x8 v;
#pragma unroll
  for (int e = 0; e < 8; ++e) v[e] = (bf16)0.0f;
  return v;
}

__device__ inline uint32_t pkbf(float a, float b) {
  uint16_t ua = __builtin_bit_cast(uint16_t, (bf16)a);
  uint16_t ub = __builtin_bit_cast(uint16_t, (bf16)b);
  return (uint32_t)ua | ((uint32_t)ub << 16);
}
__device__ inline float upk_lo(uint32_t u) { return __builtin_bit_cast(float, u << 16); }
__device__ inline float upk_hi(uint32_t u) { return __builtin_bit_cast(float, u & 0xffff0000u); }

// streaming store (nt): output is write-once, never re-read -> keep out of L2
__device__ inline void st_nt2(float* p, float a, float b) {
  f32x2 v; v[0] = a; v[1] = b;
  __builtin_nontemporal_store(v, reinterpret_cast<f32x2*>(p));
}

// ---------------- cast f32 -> bf16 (vectorized x4) ----------------
__global__ __launch_bounds__(256) void cast4(const float* __restrict__ in,
                                             bf16* __restrict__ out, int n) {
  int i = (blockIdx.x * 256 + threadIdx.x) * 4;
  if (i + 3 < n) {
    float4 v = *reinterpret_cast<const float4*>(in + i);
    bf16 tmp[4];
    tmp[0] = (bf16)v.x; tmp[1] = (bf16)v.y; tmp[2] = (bf16)v.z; tmp[3] = (bf16)v.w;
    *reinterpret_cast<uint64_t*>(out + i) = *reinterpret_cast<const uint64_t*>(tmp);
  } else {
    for (; i < n; ++i) out[i] = (bf16)in[i];
  }
}

// ---------------- q = x @ Wq^T + bq : LDS-tiled MFMA GEMM (64x128 tile, BK=32) ----------------
__global__ __launch_bounds__(256) void qgemm_t(const bf16* __restrict__ X,
                                               const bf16* __restrict__ W,
                                               const float* __restrict__ bq,
                                               bf16* __restrict__ Q) {
  __shared__ bf16 As[64 * 40];
  __shared__ bf16 Bs[128 * 40];
  int t = threadIdx.x, lane = t & 63, w = t >> 6;
  int lid = lane & 15, g = lane >> 4;
  int m0 = blockIdx.x * 64, n0 = blockIdx.y * 128;
  int wm = (w >> 1) * 32, wn = (w & 1) * 64;
  f32x4 z4 = {0.f, 0.f, 0.f, 0.f};
  f32x4 acc[2][4];
#pragma unroll
  for (int mi = 0; mi < 2; ++mi)
#pragma unroll
    for (int ni = 0; ni < 4; ++ni) acc[mi][ni] = z4;
  int r1 = t >> 2, c1 = t & 3;
  for (int k0 = 0; k0 < 1024; k0 += 32) {
    int ga = m0 + r1; if (ga >= M_) ga = M_ - 1;
    bf16x8 av = *reinterpret_cast<const bf16x8*>(X + (size_t)ga * 1024 + k0 + c1 * 8);
    bf16x8 bv1 = *reinterpret_cast<const bf16x8*>(W + (size_t)(n0 + r1) * 1024 + k0 + c1 * 8);
    bf16x8 bv2 = *reinterpret_cast<const bf16x8*>(W + (size_t)(n0 + 64 + r1) * 1024 + k0 + c1 * 8);
    __syncthreads();
    *reinterpret_cast<bf16x8*>(As + r1 * 40 + c1 * 8) = av;
    *reinterpret_cast<bf16x8*>(Bs + r1 * 40 + c1 * 8) = bv1;
    *reinterpret_cast<bf16x8*>(Bs + (64 + r1) * 40 + c1 * 8) = bv2;
    __syncthreads();
    bf16x8 af[2], bfr[4];
#pragma unroll
    for (int mi = 0; mi < 2; ++mi)
      af[mi] = *reinterpret_cast<const bf16x8*>(As + (wm + mi * 16 + lid) * 40 + g * 8);
#pragma unroll
    for (int ni = 0; ni < 4; ++ni)
      bfr[ni] = *reinterpret_cast<const bf16x8*>(Bs + (wn + ni * 16 + lid) * 40 + g * 8);
#pragma unroll
    for (int mi = 0; mi < 2; ++mi)
#pragma unroll
      for (int ni = 0; ni < 4; ++ni)
        acc[mi][ni] = __builtin_amdgcn_mfma_f32_16x16x32_bf16(af[mi], bfr[ni], acc[mi][ni], 0, 0, 0);
  }
  float bias[4];
#pragma unroll
  for (int ni = 0; ni < 4; ++ni) bias[ni] = bq[n0 + wn + ni * 16 + lid];
#pragma unroll
  for (int mi = 0; mi < 2; ++mi)
#pragma unroll
    for (int r = 0; r < 4; ++r) {
      int row = m0 + wm + mi * 16 + g * 4 + r;
      if (row < M_) {
#pragma unroll
        for (int ni = 0; ni < 4; ++ni)
          Q[(size_t)row * 1024 + n0 + wn + ni * 16 + lid] = (bf16)(acc[mi][ni][r] + bias[ni]);
      }
    }
}

// ---------------- global-head K/V projections; K row-major, V TRANSPOSED out ----------------
__global__ __launch_bounds__(256) void proj_g32(const float* __restrict__ x,
    const float* __restrict__ Wk, const float* __restrict__ bk,
    const float* __restrict__ Wv, const float* __restrict__ bv,
    bf16* __restrict__ KGP, bf16* __restrict__ VGT) {
  __shared__ float xs[64][64];
  __shared__ float wks[64][65];
  __shared__ float wvs[64][65];
  int t = threadIdx.x;
  int lb = blockIdx.x, bh = blockIdx.y;
  int b = bh >> 3, h = bh & 7;
  int l0 = lb * 64;
  for (int idx = t; idx < 4096; idx += 256) {
    int r = idx >> 6, c = idx & 63;
    int l = l0 + r;
    xs[r][c] = (l < L_) ? x[((size_t)b * L_ + l) * 1024 + h * 64 + c] : 0.0f;
    wks[r][c] = Wk[(size_t)h * 4096 + idx];
    wvs[r][c] = Wv[(size_t)h * 4096 + idx];
  }
  __syncthreads();
  int o = t & 63, lg = t >> 6;
  float kbias = bk[h * 64 + o], vbias = bv[h * 64 + o];
  float vacc[16];
  const size_t outb = (size_t)bh * LP_ * 64;
  for (int ls = 0; ls < 16; ++ls) {
    int l = lg * 16 + ls;
    float ka = kbias, va = vbias;
#pragma unroll
    for (int i = 0; i < 64; ++i) {
      float xv = xs[l][i];
      ka = fmaf(xv, wks[o][i], ka);
      va = fmaf(xv, wvs[o][i], va);
    }
    KGP[outb + (size_t)(l0 + l) * 64 + o] = (bf16)ka;
    vacc[ls] = va;
  }
  __syncthreads();
#pragma unroll
  for (int ls = 0; ls < 16; ++ls) wvs[o][lg * 16 + ls] = vacc[ls];
  __syncthreads();
  for (int idx = t; idx < 4096; idx += 256) {
    int oo = idx >> 6, ll = idx & 63;
    VGT[(size_t)bh * 64 * LP_ + (size_t)oo * LP_ + l0 + ll] = (bf16)wvs[oo][ll];
  }
}

// ---------------- local-head window-avg + K/V projections; V TRANSPOSED out ----------------
__global__ __launch_bounds__(256) void proj_l32(const float* __restrict__ x,
    const float* __restrict__ Wk, const float* __restrict__ bk,
    const float* __restrict__ Wv, const float* __restrict__ bv,
    bf16* __restrict__ KLP, bf16* __restrict__ VLT) {
  __shared__ float xs[64][64];
  __shared__ float wks[64][65];
  __shared__ float wvs[64][65];
  int t = threadIdx.x;
  int nb = blockIdx.x, bh = blockIdx.y;
  int b = bh >> 3, h = bh & 7;
  int n0 = nb * 64;
  int hh = 8 + h;
  for (int idx = t; idx < 4096; idx += 256) {
    int r = idx >> 6, c = idx & 63;
    int n = n0 + r;
    float v = 0.0f;
    if (n < NW_) {
      size_t base = ((size_t)b * L_ + 3 * n) * 1024 + hh * 64 + c;
      v = (x[base] + x[base + 1024] + x[base + 2048]) * (1.0f / 3.0f);
    }
    xs[r][c] = v;
    wks[r][c] = Wk[(size_t)hh * 4096 + idx];
    wvs[r][c] = Wv[(size_t)hh * 4096 + idx];
  }
  __syncthreads();
  int o = t & 63, lg = t >> 6;
  float kbias = bk[hh * 64 + o], vbias = bv[hh * 64 + o];
  float vacc[16];
  const size_t outb = (size_t)bh * NWP_ * 64;
  for (int ls = 0; ls < 16; ++ls) {
    int l = lg * 16 + ls;
    float ka = kbias, va = vbias;
#pragma unroll
    for (int i = 0; i < 64; ++i) {
      float xv = xs[l][i];
      ka = fmaf(xv, wks[o][i], ka);
      va = fmaf(xv, wvs[o][i], va);
    }
    KLP[outb + (size_t)(n0 + l) * 64 + o] = (bf16)ka;
    vacc[ls] = va;
  }
  __syncthreads();
#pragma unroll
  for (int ls = 0; ls < 16; ++ls) wvs[o][lg * 16 + ls] = vacc[ls];
  __syncthreads();
  for (int idx = t; idx < 4096; idx += 256) {
    int oo = idx >> 6, ll = idx & 63;
    VLT[(size_t)bh * 64 * NWP_ + (size_t)oo * NWP_ + n0 + ll] = (bf16)wvs[oo][ll];
  }
}

// ---------------- mask precompute: bit-packed (1 = masked) — R3-verified ----------------
__global__ __launch_bounds__(256) void maskprep(const float* __restrict__ mask,
                                                uint64_t* __restrict__ gm,
                                                uint64_t* __restrict__ wm) {
  int row = blockIdx.x * 4 + (threadIdx.x >> 6);  // b*L + l
  int lane = threadIdx.x & 63;
  if (row >= B_ * L_) return;
  int b = row / L_, l = row % L_;
  const float* mr = mask + (size_t)b * L_ * L_ + (size_t)l * L_;
  for (int w = 0; w < 32; ++w) {
    int m = w * 64 + lane;
    bool masked = (m >= L_) ? true : (mr[m] == 0.0f);
    uint64_t bal = __ballot(masked);
    if (lane == 0) gm[(size_t)row * 32 + w] = bal;
  }
  for (int w = 0; w < 11; ++w) {
    int n = w * 64 + lane;
    bool lmask = true;
    if (n < NW_) {
      float s = mr[3 * n] + mr[3 * n + 1] + mr[3 * n + 2];
      lmask = !(s >= 2.0f);
    }
    uint64_t bal = __ballot(lmask);
    if (lane == 0) wm[(size_t)row * 11 + w] = bal;
  }
}

// ---------------- FUSED global, 16-wave: QK^T -> softmax -> pg (nt) + PV (V^T reg-dbuf) ----------------
__global__ __launch_bounds__(1024, 4) void attn_gf(const bf16* __restrict__ Q,
    const bf16* __restrict__ K, const bf16* __restrict__ VT,
    const uint64_t* __restrict__ GM,
    float* __restrict__ OP, float* __restrict__ OV) {
  __shared__ float sums[256];
  __shared__ float pool[8704];
  int t = threadIdx.x;
  int lane = t & 63, wave = t >> 6;   // 16 waves
  int lid = lane & 15, g = lane >> 4;
  int q0 = blockIdx.x * 16;
  int bh = blockIdx.y;
  int b = bh >> 3, h = bh & 7;
  const bf16* qb = Q + (size_t)b * L_ * 1024 + h * 64;
  const bf16* kb = K + (size_t)bh * LP_ * 64;
  const bf16* vtg = VT + (size_t)bh * 64 * LP_;
  const uint64_t* gmb = GM + (size_t)b * L_ * 32;

  bf16x8 aq0 = zf8(), aq1 = zf8();
  {
    int qr = q0 + lid;
    if (qr < L_) {
      aq0 = *reinterpret_cast<const bf16x8*>(qb + (size_t)qr * 1024 + g * 8);
      aq1 = *reinterpret_cast<const bf16x8*>(qb + (size_t)qr * 1024 + 32 + g * 8);
    }
  }
  // ---- phase 1: single-pass QK^T, P in registers ----
  uint32_t preg[16];
  float rs[4] = {0.f, 0.f, 0.f, 0.f};
#pragma unroll
  for (int it = 0; it < 4; ++it) {
    int p = it * 16 + wave;
    int c0 = p * 32;
    int col0 = c0 + lid, col1 = c0 + 16 + lid;
    bf16x8 bka0 = *reinterpret_cast<const bf16x8*>(kb + (size_t)col0 * 64 + g * 8);
    bf16x8 bka1 = *reinterpret_cast<const bf16x8*>(kb + (size_t)col0 * 64 + 32 + g * 8);
    bf16x8 bkb0 = *reinterpret_cast<const bf16x8*>(kb + (size_t)col1 * 64 + g * 8);
    bf16x8 bkb1 = *reinterpret_cast<const bf16x8*>(kb + (size_t)col1 * 64 + 32 + g * 8);
    f32x4 acc0 = {0.f, 0.f, 0.f, 0.f}, acc1 = {0.f, 0.f, 0.f, 0.f};
    acc0 = __builtin_amdgcn_mfma_f32_16x16x32_bf16(aq0, bka0, acc0, 0, 0, 0);
    acc0 = __builtin_amdgcn_mfma_f32_16x16x32_bf16(aq1, bka1, acc0, 0, 0, 0);
    acc1 = __builtin_amdgcn_mfma_f32_16x16x32_bf16(aq0, bkb0, acc1, 0, 0, 0);
    acc1 = __builtin_amdgcn_mfma_f32_16x16x32_bf16(aq1, bkb1, acc1, 0, 0, 0);
    int wi = c0 >> 6;
    int bit0 = c0 & 32;
#pragma unroll
    for (int r = 0; r < 4; ++r) {
      int qr = q0 + g * 4 + r;
      uint64_t w = (qr < L_) ? gmb[(size_t)qr * 32 + wi] : ~0ull;
      float pv0 = ((w >> (bit0 + lid)) & 1) ? 0.0f : __expf(acc0[r] * SCALE_);
      float pv1 = ((w >> (bit0 + 16 + lid)) & 1) ? 0.0f : __expf(acc1[r] * SCALE_);
      rs[r] += pv0 + pv1;
      preg[it * 4 + r] = pkbf(pv0, pv1);
    }
  }
#pragma unroll
  for (int off = 8; off >= 1; off >>= 1)
#pragma unroll
    for (int r = 0; r < 4; ++r) rs[r] += __shfl_xor(rs[r], off, 64);
  if (lid == 0) {
#pragma unroll
    for (int r = 0; r < 4; ++r) sums[wave * 16 + g * 4 + r] = rs[r];
  }
  __syncthreads();
  float invr[4];
#pragma unroll
  for (int r = 0; r < 4; ++r) {
    int row = g * 4 + r;
    float s = 0.f;
#pragma unroll
    for (int ww = 0; ww < 16; ++ww) s += sums[ww * 16 + row];
    invr[r] = (s > 0.f) ? 1.0f / s : 0.0f;
  }
  // ---- phase 2: strip -> pg store (nt) + PV with register-double-buffered V ----
  f32x4 vacc[4];
  f32x4 z4 = {0.f, 0.f, 0.f, 0.f};
#pragma unroll
  for (int dg = 0; dg < 4; ++dg) vacc[dg] = z4;
  int qrW = q0 + wave;
  bool rowokW = (qrW < L_);
  const size_t rowbW = (size_t)bh * L_ * L_ + (size_t)(rowokW ? qrW : 0) * L_;
  bf16x8 bvp[4];
#pragma unroll
  for (int dg = 0; dg < 4; ++dg)
    bvp[dg] = *reinterpret_cast<const bf16x8*>(vtg + (size_t)(dg * 16 + lid) * LP_ + wave * 32 + g * 8);
#pragma unroll
  for (int it = 0; it < 4; ++it) {
    int mb0 = it * 512;
#pragma unroll
    for (int r = 0; r < 4; ++r) {
      uint32_t u = preg[it * 4 + r];
      pool[(g * 4 + r) * STR + wave * 32 + lid] = upk_lo(u) * invr[r];
      pool[(g * 4 + r) * STR + wave * 32 + 16 + lid] = upk_hi(u) * invr[r];
    }
    // prefetch next iteration's V fragments BEFORE the barrier (hides load latency)
    bf16x8 bvn[4];
    if (it < 3) {
#pragma unroll
      for (int dg = 0; dg < 4; ++dg)
        bvn[dg] = *reinterpret_cast<const bf16x8*>(vtg + (size_t)(dg * 16 + lid) * LP_ + (mb0 + 512) + wave * 32 + g * 8);
    }
    __syncthreads();
    bf16x8 af;
#pragma unroll
    for (int e = 0; e < 8; ++e) af[e] = (bf16)pool[lid * STR + wave * 32 + g * 8 + e];
#pragma unroll
    for (int dg = 0; dg < 4; ++dg)
      vacc[dg] = __builtin_amdgcn_mfma_f32_16x16x32_bf16(af, bvp[dg], vacc[dg], 0, 0, 0);
    if (rowokW) {
#pragma unroll
      for (int seg = 0; seg < 4; ++seg) {
        int cc = seg * 128 + lane * 2;
        int col = mb0 + cc;
        if (col + 1 < L_)
          st_nt2(OP + rowbW + col, pool[wave * STR + cc], pool[wave * STR + cc + 1]);
      }
    }
    __syncthreads();
#pragma unroll
    for (int dg = 0; dg < 4; ++dg) bvp[dg] = bvn[dg];
  }
  // ---- cross-wave OV reduce: log tree in pool ----
#pragma unroll
  for (int s = 8; s >= 1; s >>= 1) {
    if (wave >= s && wave < 2 * s) {
#pragma unroll
      for (int dg = 0; dg < 4; ++dg)
#pragma unroll
        for (int r = 0; r < 4; ++r)
          pool[(wave - s) * RW + (g * 4 + r) * RSTR + dg * 16 + lid] = vacc[dg][r];
    }
    __syncthreads();
    if (wave < s) {
#pragma unroll
      for (int dg = 0; dg < 4; ++dg)
#pragma unroll
        for (int r = 0; r < 4; ++r)
          vacc[dg][r] += pool[wave * RW + (g * 4 + r) * RSTR + dg * 16 + lid];
    }
    __syncthreads();
  }
  if (wave == 0) {
    float* ob = OV + (((size_t)b * 16 + h) * L_) * 64;
#pragma unroll
    for (int dg = 0; dg < 4; ++dg)
#pragma unroll
      for (int r = 0; r < 4; ++r) {
        int qr = q0 + g * 4 + r;
        if (qr < L_) __builtin_nontemporal_store(vacc[dg][r], ob + (size_t)qr * 64 + dg * 16 + lid);
      }
  }
}

// ---------------- FUSED local, 16-wave (V^T reg-dbuf) ----------------
__global__ __launch_bounds__(1024, 4) void attn_lf(const bf16* __restrict__ Q,
    const bf16* __restrict__ K, const bf16* __restrict__ VT,
    const uint64_t* __restrict__ WM,
    float* __restrict__ OP, float* __restrict__ OV) {
  __shared__ float sums[256];
  __shared__ float pool[8704];
  int t = threadIdx.x;
  int lane = t & 63, wave = t >> 6;
  int lid = lane & 15, g = lane >> 4;
  int q0 = blockIdx.x * 16;
  int bh = blockIdx.y;
  int b = bh >> 3, h = bh & 7;
  const bf16* qb = Q + (size_t)b * L_ * 1024 + (8 + h) * 64;
  const bf16* kb = K + (size_t)bh * NWP_ * 64;
  const bf16* vtg = VT + (size_t)bh * 64 * NWP_;
  const uint64_t* wmb = WM + (size_t)b * L_ * 11;

  bf16x8 aq0 = zf8(), aq1 = zf8();
  {
    int qr = q0 + lid;
    if (qr < L_) {
      aq0 = *reinterpret_cast<const bf16x8*>(qb + (size_t)qr * 1024 + g * 8);
      aq1 = *reinterpret_cast<const bf16x8*>(qb + (size_t)qr * 1024 + 32 + g * 8);
    }
  }
  uint32_t preg[8];
  float rs[4] = {0.f, 0.f, 0.f, 0.f};
#pragma unroll
  for (int it = 0; it < 2; ++it) {
    int p = it * 16 + wave;
    if (p < 22) {
      int c0 = p * 32;
      int col0 = c0 + lid, col1 = c0 + 16 + lid;
      bf16x8 bka0 = *reinterpret_cast<const bf16x8*>(kb + (size_t)col0 * 64 + g * 8);
      bf16x8 bka1 = *reinterpret_cast<const bf16x8*>(kb + (size_t)col0 * 64 + 32 + g * 8);
      bf16x8 bkb0 = *reinterpret_cast<const bf16x8*>(kb + (size_t)col1 * 64 + g * 8);
      bf16x8 bkb1 = *reinterpret_cast<const bf16x8*>(kb + (size_t)col1 * 64 + 32 + g * 8);
      f32x4 acc0 = {0.f, 0.f, 0.f, 0.f}, acc1 = {0.f, 0.f, 0.f, 0.f};
      acc0 = __builtin_amdgcn_mfma_f32_16x16x32_bf16(aq0, bka0, acc0, 0, 0, 0);
      acc0 = __builtin_amdgcn_mfma_f32_16x16x32_bf16(aq1, bka1, acc0, 0, 0, 0);
      acc1 = __builtin_amdgcn_mfma_f32_16x16x32_bf16(aq0, bkb0, acc1, 0, 0, 0);
      acc1 = __builtin_amdgcn_mfma_f32_16x16x32_bf16(aq1, bkb1, acc1, 0, 0, 0);
      int wi = c0 >> 6;
      int bit0 = c0 & 32;
#pragma unroll
      for (int r = 0; r < 4; ++r) {
        int qr = q0 + g * 4 + r;
        uint64_t w = (qr < L_) ? wmb[(size_t)qr * 11 + wi] : ~0ull;
        float pv0 = ((w >> (bit0 + lid)) & 1) ? 0.0f : __expf(acc0[r] * SCALE_);
        float pv1 = ((w >> (bit0 + 16 + lid)) & 1) ? 0.0f : __expf(acc1[r] * SCALE_);
        rs[r] += pv0 + pv1;
        preg[it * 4 + r] = pkbf(pv0, pv1);
      }
    }
  }
#pragma unroll
  for (int off = 8; off >= 1; off >>= 1)
#pragma unroll
    for (int r = 0; r < 4; ++r) rs[r] += __shfl_xor(rs[r], off, 64);
  if (lid == 0) {
#pragma unroll
    for (int r = 0; r < 4; ++r) sums[wave * 16 + g * 4 + r] = rs[r];
  }
  __syncthreads();
  float invr[4];
#pragma unroll
  for (int r = 0; r < 4; ++r) {
    int row = g * 4 + r;
    float s = 0.f;
#pragma unroll
    for (int ww = 0; ww < 16; ++ww) s += sums[ww * 16 + row];
    invr[r] = (s > 0.f) ? 1.0f / s : 0.0f;
  }
  f32x4 vacc[4];
  f32x4 z4 = {0.f, 0.f, 0.f, 0.f};
#pragma unroll
  for (int dg = 0; dg < 4; ++dg) vacc[dg] = z4;
  int qrW = q0 + wave;
  bool rowokW = (qrW < L_);
  const size_t rowbW = (size_t)bh * L_ * NW_ + (size_t)(rowokW ? qrW : 0) * NW_;
  bf16x8 bvp[4];
  bool act0 = (wave < 22);
  if (act0) {
#pragma unroll
    for (int dg = 0; dg < 4; ++dg)
      bvp[dg] = *reinterpret_cast<const bf16x8*>(vtg + (size_t)(dg * 16 + lid) * NWP_ + wave * 32 + g * 8);
  }
#pragma unroll
  for (int it = 0; it < 2; ++it) {
    int p = it * 16 + wave;
    bool act = (p < 22);
    int mb0 = it * 512;
    if (act) {
#pragma unroll
      for (int r = 0; r < 4; ++r) {
        uint32_t u = preg[it * 4 + r];
        pool[(g * 4 + r) * STR + wave * 32 + lid] = upk_lo(u) * invr[r];
        pool[(g * 4 + r) * STR + wave * 32 + 16 + lid] = upk_hi(u) * invr[r];
      }
    }
    // prefetch next iteration's V (only if next p active)
    bf16x8 bvn[4];
    if (it < 1 && (16 + wave) < 22) {
#pragma unroll
      for (int dg = 0; dg < 4; ++dg)
        bvn[dg] = *reinterpret_cast<const bf16x8*>(vtg + (size_t)(dg * 16 + lid) * NWP_ + 512 + wave * 32 + g * 8);
    }
    __syncthreads();
    if (act) {
      bf16x8 af;
#pragma unroll
      for (int e = 0; e < 8; ++e) af[e] = (bf16)pool[lid * STR + wave * 32 + g * 8 + e];
#pragma unroll
      for (int dg = 0; dg < 4; ++dg)
        vacc[dg] = __builtin_amdgcn_mfma_f32_16x16x32_bf16(af, bvp[dg], vacc[dg], 0, 0, 0);
    }
    if (rowokW) {
#pragma unroll
      for (int seg = 0; seg < 4; ++seg) {
        int cc = seg * 128 + lane * 2;
        int col = mb0 + cc;
        if (col + 1 < NW_)
          st_nt2(OP + rowbW + col, pool[wave * STR + cc], pool[wave * STR + cc + 1]);
      }
    }
    __syncthreads();
#pragma unroll
    for (int dg = 0; dg < 4; ++dg) bvp[dg] = bvn[dg];
  }
#pragma unroll
  for (int s = 8; s >= 1; s >>= 1) {
    if (wave >= s && wave < 2 * s) {
#pragma unroll
      for (int dg = 0; dg < 4; ++dg)
#pragma unroll
        for (int r = 0; r < 4; ++r)
          pool[(wave - s) * RW + (g * 4 + r) * RSTR + dg * 16 + lid] = vacc[dg][r];
    }
    __syncthreads();
    if (wave < s) {
#pragma unroll
      for (int dg = 0; dg < 4; ++dg)
#pragma unroll
        for (int r = 0; r < 4; ++r)
          vacc[dg][r] += pool[wave * RW + (g * 4 + r) * RSTR + dg * 16 + lid];
    }
    __syncthreads();
  }
  if (wave == 0) {
    float* ob = OV + (((size_t)b * 16 + 8 + h) * L_) * 64;
#pragma unroll
    for (int dg = 0; dg < 4; ++dg)
#pragma unroll
      for (int r = 0; r < 4; ++r) {
        int qr = q0 + g * 4 + r;
        if (qr < L_) __builtin_nontemporal_store(vacc[dg][r], ob + (size_t)qr * 64 + dg * 16 + lid);
      }
  }
}

extern "C" void kernel_launch(void* const* d_in, const int* in_sizes, int n_in,
                              void* d_out, int out_size, void* d_ws, size_t ws_size,
                              hipStream_t stream) {
  (void)in_sizes; (void)n_in; (void)out_size; (void)ws_size;
  const float* x    = (const float*)d_in[0];
  const float* mask = (const float*)d_in[1];
  const float* Wq   = (const float*)d_in[2];
  const float* bq   = (const float*)d_in[3];
  const float* Wk   = (const float*)d_in[4];
  const float* bk   = (const float*)d_in[5];
  const float* Wv   = (const float*)d_in[6];
  const float* bv   = (const float*)d_in[7];

  char* ws = (char*)d_ws;
  bf16* qbb     = (bf16*)(ws + 0);            // 8,380,416
  bf16* kgb     = (bf16*)(ws + 8380416);      // 4,194,304
  bf16* vgT     = (bf16*)(ws + 12574720);     // 4,194,304 (V^T [bh][d][m])
  bf16* klb     = (bf16*)(ws + 16769024);     // 1,441,792
  bf16* vlT     = (bf16*)(ws + 18210816);     // 1,441,792 (V^T local)
  uint64_t* gm  = (uint64_t*)(ws + 19652608); // 1,047,552
  uint64_t* wm  = (uint64_t*)(ws + 20700160); // 360,096
  bf16* xbb     = (bf16*)(ws + 21060256);     // 8,380,416 (x in bf16)
  bf16* wqb     = (bf16*)(ws + 29440672);     // 2,097,152 (Wq in bf16)

  float* out    = (float*)d_out;
  float* o_vall = out;                 // (2,16,2046,64)
  float* o_pg   = out + 4190208;       // (2,8,2046,2046)
  float* o_pl   = out + 71168064;      // (2,8,2046,682)

  cast4<<<4092, 256, 0, stream>>>(x, xbb, 4190208);
  cast4<<<1024, 256, 0, stream>>>(Wq, wqb, 1048576);
  qgemm_t<<<dim3(64, 8), 256, 0, stream>>>(xbb, wqb, bq, qbb);
  proj_g32<<<dim3(32, 16), 256, 0, stream>>>(x, Wk, bk, Wv, bv, kgb, vgT);
  proj_l32<<<dim3(11, 16), 256, 0, stream>>>(x, Wk, bk, Wv, bv, klb, vlT);
  maskprep<<<1023, 256, 0, stream>>>(mask, gm, wm);

  attn_gf<<<dim3(128, 16), 1024, 0, stream>>>(qbb, kgb, vgT, gm, o_pg, o_vall);
  attn_lf<<<dim3(128, 16), 1024, 0, stream>>>(qbb, klb, vlT, wm, o_pl, o_vall);
}